// Round 1
// baseline (841.219 us; speedup 1.0000x reference)
//
#include <hip/hip_runtime.h>
#include <math.h>

typedef unsigned short u16;
typedef unsigned int   u32;
typedef unsigned long long u64;
typedef __attribute__((ext_vector_type(8))) short short8;   // 8 bf16 (4 VGPR)
typedef __attribute__((ext_vector_type(4))) float f32x4;    // MFMA acc

// ---------- dtype helpers ----------
__device__ __forceinline__ float b2f(u16 v) { return __uint_as_float(((u32)v) << 16); }
__device__ __forceinline__ u16 f2b(float f) {
    u32 u = __float_as_uint(f);
    u32 r = (u + 0x7FFFu + ((u >> 16) & 1u)) >> 16;   // RNE
    return (u16)r;
}
__device__ __forceinline__ float gload(const void* p, long i, int bf) {
    return bf ? b2f(((const u16*)p)[i]) : ((const float*)p)[i];
}
__device__ __forceinline__ void gstore(void* p, long i, float v, int bf) {
    if (bf) ((u16*)p)[i] = f2b(v);
    else    ((float*)p)[i] = v;
}

// top-k key: smallest key = (largest value, then smallest index)
__device__ __forceinline__ u64 packKey(float v, int idx) {
    u32 u = __float_as_uint(v);
    u32 m = (u & 0x80000000u) ? ~u : (u | 0x80000000u);   // monotone float->uint
    return ((u64)(~m) << 32) | (u32)idx;
}

// per-block dtype-flag recompute (512 u16 probe of feat)
__device__ int blockFlag(const void* feat) {
    __shared__ int fcnt;
    if (threadIdx.x == 0) fcnt = 0;
    __syncthreads();
    int sane = 0;
    for (int i = threadIdx.x; i < 512; i += blockDim.x) {
        u16 v = ((const u16*)feat)[i];
        float f = b2f(v);
        u32 e = (v >> 7) & 0xFF;
        float a = fabsf(f);
        sane += (e != 0xFF) && (f == 0.f || (a >= 1e-8f && a <= 1e4f));
    }
    atomicAdd(&fcnt, sane);
    __syncthreads();
    return fcnt >= 480;
}

// ---------- problem constants ----------
#define BATCH 8
#define CIN   64
#define FH    96
#define FW    320
#define KDET  50
#define NROI  400
#define CROI  69
#define HW    (FH*FW)
#define CHUNK 1920
#define NCHUNK 16

// ---------- workspace layout (float offsets) ----------
#define WS_HEAT 0L
#define WS_OFF2 737280L
#define WS_SIZ2 1228800L
#define WS_NH   1720320L
#define WS_CLS  2460000L
#define WS_BOX  2460400L
#define WS_ROI  2462400L
#define WS_HOUT 3814800L
#define WS_W1T  3827600L     // 147456 f32: hm conv1 [k=576][c=256] (exact strip)
#define WS_WB16 3975056L     // u16: 3 branches * [9][2][256][32] bf16 (lane-coalesced)
#define WS_W1H  4269968L     // u16: 4 heads * [9][3][256][32] bf16
#define WS_PAR  4905872L     // packed f32 params
#define WS_FLAG 4938960L     // int dtype flag
#define WS_FEATT 4938964L    // u16: [8][96][320][64] bf16 transposed features
#define WS_END  (WS_FEATT + 7864320L)

// param block sub-offsets
#define PB_CAL 0
#define PB_CRN 96
#define PB_MSZ 128
#define PB_BR0 144          // stride 1040: b1@0, w2@256 ([k][n]), b2@256+OC*256
#define PB_HD0 3264         // stride 7456

// ---------- output layout (element offsets) ----------
#define O_HEAT 0L
#define O_OFF2 737280L
#define O_SIZ2 1228800L
#define O_HEAD 1720320L
#define O_DEP  1729920L
#define O_OFF3 1730720L
#define O_S3D  1731520L
#define O_H3D  1732720L

// =====================================================================
// Fused prep: weights + params + flag
// =====================================================================
struct WPtrs { const void* bw[3]; const void* hw[4]; };
struct Seg { const void* src; int n; int dst; };
struct Segs { Seg s[40]; int cnt; };

__global__ void kPrepWP(WPtrs P, Segs S, const void* __restrict__ feat,
                        int* __restrict__ flag, float* __restrict__ w1t,
                        u16* __restrict__ wb16, u16* __restrict__ whb,
                        float* __restrict__ par) {
    const int bf = blockFlag(feat);
    if (blockIdx.x == 0 && threadIdx.x == 0) *flag = bf;
    if (blockIdx.x < 5760) {
        int idx = blockIdx.x * 256 + threadIdx.x;
        if (idx < 147456) {
            int k = idx >> 8, c = idx & 255;
            w1t[idx] = gload(P.bw[0], (long)c * 576 + k, bf);
        } else if (idx < 589824) {
            int j = idx - 147456;
            int br = j / 147456, rem = j % 147456;
            int tap = rem / 16384;
            int r2 = rem & 16383;
            int s = r2 >> 13;
            int n = (r2 >> 5) & 255;
            int c5 = r2 & 31;
            int ci = s * 32 + c5;
            wb16[j] = f2b(gload(P.bw[br], (long)n * 576 + ci * 9 + tap, bf));
        } else {
            int j = idx - 589824;               // < 884736
            int h = j / 221184, rem = j % 221184;
            int tap = rem / 24576, rem2 = rem % 24576;
            int cs = rem2 / 8192, rem3 = rem2 % 8192;
            int oc = rem3 >> 5, jj = rem3 & 31;
            int ci = cs * 32 + jj;
            u16 val = 0;
            if (ci < CROI) val = f2b(gload(P.hw[h], (long)oc * 621 + ci * 9 + tap, bf));
            whb[j] = val;
        }
    } else {
        int sidx = blockIdx.x - 5760;
        if (sidx < S.cnt) {
            Seg sg = S.s[sidx];
            for (int i = threadIdx.x; i < sg.n; i += 256)
                par[sg.dst + i] = gload(sg.src, i, bf);
        }
    }
}

// =====================================================================
// Mega branch dispatch: grid (5, 48, 9)
//   z==0 : exact f32 strip role (heat rows 0..2) -- dispatched FIRST so
//          its long blocks overlap the conv wave instead of tailing
//   z>=1 : MFMA conv role (b=z-1); heat stores skip rows 0..2; also
//          emits featT directly from its LDS staging tile (doT)
// =====================================================================
union MLds {
    struct { u16 a[4][68][72]; float red[2][8][64][3]; } c;   // red double-buffered
    struct {
        float in[4][3][36];
        union { float w[36 * 256]; float part[32 * 3 * 32]; } u;
    } s;
};

__global__ __launch_bounds__(512, 4)
void kBranch3M(const void* __restrict__ feat, const int* __restrict__ flag,
               const u16* __restrict__ wbAll,   // 3 * [9][2][256][32] bf16
               const float* __restrict__ bpAll, // par + PB_BR0, stride 1040
               const float* __restrict__ w1t,   // strip weights f32
               void* __restrict__ outb, float* __restrict__ wsbase, int doT) {
    __shared__ __align__(16) MLds L;

    const long obase[3] = {O_HEAT, O_OFF2, O_SIZ2};
    const long wfs[3]   = {WS_HEAT, WS_OFF2, WS_SIZ2};

    const int bfl = *flag;
    const int tid = threadIdx.x;

    if (blockIdx.z == 0) {
        // ================= STRIP ROLE (exact f32, rows 0..2) ==========
        const int sidx = blockIdx.y * 5 + blockIdx.x;   // 0..239
        const int x0 = (sidx % 10) * 32;
        const int srem = sidx / 10;
        const int y = srem % 3;
        const int b = srem / 3;
        const float* bp = bpAll;                        // heat branch params
        const int OC = 3;
        const int xg = tid & 7, cg = tid >> 3;
        const int c0 = (cg & 31) * 8;

        float acc[8][4];
#pragma unroll
        for (int i = 0; i < 8; ++i)
#pragma unroll
            for (int j = 0; j < 4; ++j) acc[i][j] = 0.f;

        for (int chunk = 0; chunk < 16; ++chunk) {
            const int ci0 = chunk * 4;
            __syncthreads();
            for (int i = tid; i < 4 * 3 * 36; i += 512) {
                int xx = i % 36, t2 = i / 36;
                int r = t2 % 3, ci = t2 / 3;
                int gx = x0 - 1 + xx, gy = y - 1 + r;
                float v = 0.f;
                if (gx >= 0 && gx < FW && gy >= 0 && gy < FH)
                    v = gload(feat, ((long)(b * CIN + ci0 + ci) * FH + gy) * FW + gx, bfl);
                L.s.in[ci][r][xx] = v;
            }
            {
                const float4* src = (const float4*)(w1t + (long)ci0 * 9 * 256);
                float4* dst = (float4*)L.s.u.w;
                for (int i = tid; i < 36 * 256 / 4; i += 512) dst[i] = src[i];
            }
            __syncthreads();
            if (tid < 256) {
#pragma unroll
                for (int ci = 0; ci < 4; ++ci) {
#pragma unroll
                    for (int ky = 0; ky < 3; ++ky) {
                        const float* rowp = &L.s.in[ci][ky][xg * 4];
                        float inv[6];
                        *(float4*)&inv[0] = *(const float4*)&rowp[0];
                        *(float2*)&inv[4] = *(const float2*)&rowp[4];
#pragma unroll
                        for (int kx = 0; kx < 3; ++kx) {
                            const float* wp = &L.s.u.w[(ci * 9 + ky * 3 + kx) * 256 + c0];
                            float wv[8];
                            *(float4*)&wv[0] = *(const float4*)&wp[0];
                            *(float4*)&wv[4] = *(const float4*)&wp[4];
#pragma unroll
                            for (int cc = 0; cc < 8; ++cc)
#pragma unroll
                                for (int xx = 0; xx < 4; ++xx)
                                    acc[cc][xx] = fmaf(wv[cc], inv[xx + kx], acc[cc][xx]);
                        }
                    }
                }
            }
        }

        if (tid < 256) {
#pragma unroll
            for (int cc = 0; cc < 8; ++cc) {
                float b1v = bp[c0 + cc];
#pragma unroll
                for (int xx = 0; xx < 4; ++xx)
                    acc[cc][xx] = fmaxf(acc[cc][xx] + b1v, 0.f);
            }
        }
        __syncthreads();
        if (tid < 256) {
#pragma unroll
            for (int k = 0; k < OC; ++k) {
                float p[4];
#pragma unroll
                for (int xx = 0; xx < 4; ++xx) p[xx] = 0.f;
#pragma unroll
                for (int cc = 0; cc < 8; ++cc) {
                    float wv = bp[256 + k * 256 + c0 + cc];
#pragma unroll
                    for (int xx = 0; xx < 4; ++xx) p[xx] = fmaf(acc[cc][xx], wv, p[xx]);
                }
#pragma unroll
                for (int xx = 0; xx < 4; ++xx)
                    L.s.u.part[((cg & 31) * OC + k) * 32 + xg * 4 + xx] = p[xx];
            }
        }
        __syncthreads();
        float* outf = wsbase + WS_HEAT;
        for (int t = tid; t < OC * 32; t += 512) {
            int k = t >> 5, xx = t & 31;
            float s = bp[256 + OC * 256 + k];
#pragma unroll 8
            for (int g = 0; g < 32; ++g) s += L.s.u.part[(g * OC + k) * 32 + xx];
            long o = (((long)b * OC + k) * FH + y) * FW + x0 + xx;
            gstore(outb, O_HEAT + o, s, bfl);
            outf[o] = s;
        }
        return;
    }

    // ==================== CONV ROLE (MFMA) ============================
    const int wave = tid >> 6, lane = tid & 63;
    const int q = lane >> 4, n15 = lane & 15;
    const int mg = wave >> 2, ng = wave & 3;
    const int x0 = blockIdx.x * 64, y0 = blockIdx.y * 2;
    const int b = blockIdx.z - 1;

    if (tid < 256) {
        const int ci = tid & 63, rr = tid >> 6;
        const int gy = y0 - 1 + rr;
        if (gy < 0 || gy >= FH) {
            for (int xi = 0; xi < 66; ++xi) L.c.a[rr][xi][ci] = 0;
        } else if (bfl) {
            const u16* rp = (const u16*)feat + ((long)((b << 6) | ci) * FH + gy) * FW;
            for (int j = 0; j < 10; ++j) {
                int xs0 = x0 - 8 + j * 8;
                u16 tmp[8];
                if (xs0 >= 0 && xs0 <= FW - 8)
                    *(uint4*)tmp = *(const uint4*)(rp + xs0);
                else
                    for (int e = 0; e < 8; ++e) {
                        int gx = xs0 + e;
                        tmp[e] = (gx >= 0 && gx < FW) ? rp[gx] : (u16)0;
                    }
                for (int e = 0; e < 8; ++e) {
                    int xi = xs0 + e - x0 + 1;
                    if (xi >= 0 && xi < 66) L.c.a[rr][xi][ci] = tmp[e];
                }
            }
        } else {
            const float* rp = (const float*)feat + ((long)((b << 6) | ci) * FH + gy) * FW;
            for (int j = 0; j < 18; ++j) {
                int xs0 = x0 - 4 + j * 4;
                float tmp[4];
                if (xs0 >= 0 && xs0 <= FW - 4)
                    *(float4*)tmp = *(const float4*)(rp + xs0);
                else
                    for (int e = 0; e < 4; ++e) {
                        int gx = xs0 + e;
                        tmp[e] = (gx >= 0 && gx < FW) ? rp[gx] : 0.f;
                    }
                for (int e = 0; e < 4; ++e) {
                    int xi = xs0 + e - x0 + 1;
                    if (xi >= 0 && xi < 66) L.c.a[rr][xi][ci] = f2b(tmp[e]);
                }
            }
        }
    }
    __syncthreads();   // a_lds visible; read-only from here on

    // ---- emit transposed features directly from the staged LDS tile ----
    // rows y0..y0+1 = LDS rr 1..2, x0..x0+63 = xi 1..64: exactly the
    // interior (in-range, identical bf16 values as the old transpose role).
    if (doT) {
        u16* featT = (u16*)(wsbase + WS_FEATT);
        for (int i = tid; i < 1024; i += 512) {           // 2 rows * 64 x * 8 c8
            int c8 = i & 7, x = (i >> 3) & 63, r = i >> 9;
            uint4 v = *(const uint4*)&L.c.a[1 + r][1 + x][c8 * 8];
            *(uint4*)(featT + (((long)b * FH + y0 + r) * FW + x0 + x) * 64 + c8 * 8) = v;
        }
    }

    const u16* aflat = &L.c.a[0][0][0];
    const int wlane = (ng * 64 + n15) * 32 + q * 8;       // n-part of weight addr
    const int abase = mg * 4896 + n15 * 72 + q * 8;       // a[4][68][72] flat base

    // software-pipelined loads: double-buffered A and B fragments.
    // half-N tiling (2 passes of 2 n-frags) keeps acc at 32 VGPR so the
    // prefetch buffers fit under the launch_bounds(512,4) cap of 128.
#define LOADB2(k, dst) { \
    const u16* wk_ = wph + (k) * 8192; \
    dst[0] = *(const short8*)(wk_); \
    dst[1] = *(const short8*)(wk_ + 512); }
#define LOADA4(k, dst) { \
    const int tap_ = (k) >> 1, s_ = (k) & 1; \
    const int ky_ = tap_ / 3, kx_ = tap_ - 3 * ky_; \
    const u16* ap_ = aflat + abase + ky_ * 4896 + kx_ * 72 + s_ * 32; \
    dst[0] = *(const short8*)(ap_); \
    dst[1] = *(const short8*)(ap_ + 1152); \
    dst[2] = *(const short8*)(ap_ + 2304); \
    dst[3] = *(const short8*)(ap_ + 3456); }
#define MFMA42(afr, bfr) { \
    _Pragma("unroll") \
    for (int i_ = 0; i_ < 4; ++i_) { \
        _Pragma("unroll") \
        for (int t_ = 0; t_ < 2; ++t_) \
            acc[i_][t_] = __builtin_amdgcn_mfma_f32_16x16x32_bf16( \
                afr[i_], bfr[t_], acc[i_][t_], 0, 0, 0); } }

#pragma unroll 1
    for (int br = 0; br < 3; ++br) {
        const int oc = (br == 0) ? 3 : 2;
        const u16* wpt = wbAll + br * 147456;
        const float* bp = bpAll + br * 1040;
        float (*redb)[64][3] = L.c.red[br & 1];

#pragma unroll 1
        for (int hf = 0; hf < 2; ++hf) {
            const u16* wph = wpt + wlane + hf * 1024;

            f32x4 acc[4][2];
#pragma unroll
            for (int i = 0; i < 4; ++i)
#pragma unroll
                for (int t = 0; t < 2; ++t) acc[i][t] = (f32x4){0.f, 0.f, 0.f, 0.f};

            short8 aA[4], aB[4], bA[2], bB[2];
            LOADB2(0, bA);
            LOADA4(0, aA);
#pragma unroll 1
            for (int st = 0; st < 18; st += 2) {
                LOADB2(st + 1, bB);
                LOADA4(st + 1, aB);
                MFMA42(aA, bA);
                if (st + 2 < 18) { LOADB2(st + 2, bA); LOADA4(st + 2, aA); }
                MFMA42(aB, bB);
            }

            // epilogue for this n-half: bias+relu+1x1 partials, reduce over
            // n15, accumulate into red (hf==0 assigns, hf==1 adds; same wave
            // owns its red slice -> no barrier between halves)
            float b1v[2], w2v[3][2];
#pragma unroll
            for (int t = 0; t < 2; ++t) {
                int n = ng * 64 + (hf * 2 + t) * 16 + n15;
                b1v[t] = bp[n];
#pragma unroll
                for (int k = 0; k < 3; ++k) w2v[k][t] = bp[256 + k * 256 + n];
            }
#pragma unroll
            for (int i = 0; i < 4; ++i) {
#pragma unroll
                for (int r = 0; r < 4; ++r) {
                    float pk[3] = {0.f, 0.f, 0.f};
#pragma unroll
                    for (int t = 0; t < 2; ++t) {
                        float h = fmaxf(acc[i][t][r] + b1v[t], 0.f);
#pragma unroll
                        for (int k = 0; k < 3; ++k) pk[k] = fmaf(h, w2v[k][t], pk[k]);
                    }
#pragma unroll
                    for (int k = 0; k < 3; ++k) {
                        pk[k] += __shfl_xor(pk[k], 1);
                        pk[k] += __shfl_xor(pk[k], 2);
                        pk[k] += __shfl_xor(pk[k], 4);
                        pk[k] += __shfl_xor(pk[k], 8);
                    }
                    if (n15 == 0) {
                        int ml = i * 16 + q * 4 + r;
                        if (hf == 0) {
#pragma unroll
                            for (int k = 0; k < 3; ++k) redb[wave][ml][k] = pk[k];
                        } else {
#pragma unroll
                            for (int k = 0; k < 3; ++k) redb[wave][ml][k] += pk[k];
                        }
                    }
                }
            }
        }

        __syncthreads();   // redb[br&1] complete (single barrier per branch;
                           // buffer alternation makes write-after-read safe)
        float* outf = wsbase + wfs[br];
        for (int t2 = tid; t2 < oc * 128; t2 += 512) {
            int k = t2 >> 7, m = t2 & 127;
            int row = m >> 6, x = m & 63;
            int mg2 = m >> 6, ml = m & 63;
            float s = bp[256 + oc * 256 + k];
#pragma unroll
            for (int w = 0; w < 4; ++w) s += redb[mg2 * 4 + w][ml][k];
            int grow = y0 + row;
            if (br == 0 && grow < 3) continue;    // strip role owns heat rows 0..2
            long o = (((long)b * oc + k) * FH + grow) * FW + x0 + x;
            gstore(outb, obase[br] + o, s, bfl);
            outf[o] = s;
        }
    }
#undef LOADB2
#undef LOADA4
#undef MFMA42
}

// =====================================================================
// Fused NMS + top-k stage A (4-wave hierarchical extraction)
// =====================================================================
__global__ __launch_bounds__(256)
void kNmsTopA(const float* __restrict__ heat, float* __restrict__ nh) {
    __shared__ float hrow[8][320];
    __shared__ u64 keys[CHUNK];
    __shared__ u64 sub[4][KDET];
    const int bc = blockIdx.x, ch = blockIdx.y;
    const int tid = threadIdx.x;
    const int wave = tid >> 6, lane = tid & 63;
    const int r0 = ch * 6;
    const float* hp = heat + (long)bc * HW;

    for (int i = tid; i < 8 * 320; i += 256) {
        int rr = i / 320, x = i % 320;
        int gy = r0 - 1 + rr;
        hrow[rr][x] = (gy >= 0 && gy < FH) ? hp[(long)gy * FW + x] : -INFINITY;
    }
    __syncthreads();
    for (int i = tid; i < CHUNK; i += 256) {
        int ry = i / 320, x = i % 320;
        float v = hrow[ry + 1][x];
        float m = v;
        int xm = max(x - 1, 0), xp = min(x + 1, FW - 1);
#pragma unroll
        for (int dy = 0; dy < 3; ++dy) {
            m = fmaxf(m, hrow[ry + dy][xm]);
            m = fmaxf(m, hrow[ry + dy][x]);
            m = fmaxf(m, hrow[ry + dy][xp]);
        }
        float nv = (v == m) ? v : 0.f;
        keys[i] = packKey(nv, ch * CHUNK + i);
    }
    __syncthreads();
    // each wave: top-50 of its 480-element sub-chunk
    {
        u64* kw = keys + wave * 480;
        for (int it = 0; it < KDET; ++it) {
            u64 bk = ~0ULL; int bp = 0;
            for (int i = lane; i < 480; i += 64) {
                u64 k = kw[i];
                if (k < bk) { bk = k; bp = i; }
            }
#pragma unroll
            for (int s = 32; s > 0; s >>= 1) {
                u64 k2 = __shfl_down(bk, s);
                int p2 = __shfl_down(bp, s);
                if (k2 < bk) { bk = k2; bp = p2; }
            }
            bk = __shfl(bk, 0);
            bp = __shfl(bp, 0);
            if (lane == 0) {
                sub[wave][it] = bk;
                kw[bp] = ~0ULL;
            }
        }
    }
    __syncthreads();
    // wave 0: merge 4x50 -> chunk top-50
    if (wave == 0) {
        u64* outp = (u64*)(nh + (long)bc * HW + (long)ch * CHUNK);
        u64* sp = &sub[0][0];
        for (int it = 0; it < KDET; ++it) {
            u64 bk = ~0ULL; int bp = 0;
            for (int i = lane; i < 4 * KDET; i += 64) {
                u64 k = sp[i];
                if (k < bk) { bk = k; bp = i; }
            }
#pragma unroll
            for (int s = 32; s > 0; s >>= 1) {
                u64 k2 = __shfl_down(bk, s);
                int p2 = __shfl_down(bp, s);
                if (k2 < bk) { bk = k2; bp = p2; }
            }
            bk = __shfl(bk, 0);
            bp = __shfl(bp, 0);
            if (lane == 0) {
                outp[it] = bk;
                sp[bp] = ~0ULL;
            }
        }
    }
}

// =====================================================================
// Fused top-k stage B + stage 2 + boxes
// =====================================================================
__global__ __launch_bounds__(192)
void kTopBC(const float* __restrict__ nh, const float* __restrict__ off2,
            const float* __restrict__ siz2, float* __restrict__ boxes,
            int* __restrict__ clsArr) {
    __shared__ u64 keys[3][NCHUNK * KDET];
    __shared__ float sc[150];
    __shared__ int   si[150];
    const int b = blockIdx.x, tid = threadIdx.x;
    const int wave = tid >> 6, lane = tid & 63;
    const int bc = b * 3 + wave;

    for (int ch = 0; ch < NCHUNK; ++ch) {
        const u64* src = (const u64*)(nh + (long)bc * HW + (long)ch * CHUNK);
        if (lane < KDET) keys[wave][ch * KDET + lane] = src[lane];
    }
    __syncthreads();
    for (int it = 0; it < KDET; ++it) {
        u64 bk = ~0ULL; int bp = 0;
        for (int i = lane; i < NCHUNK * KDET; i += 64) {
            u64 k = keys[wave][i];
            if (k < bk) { bk = k; bp = i; }
        }
#pragma unroll
        for (int s = 32; s > 0; s >>= 1) {
            u64 k2 = __shfl_down(bk, s);
            int p2 = __shfl_down(bp, s);
            if (k2 < bk) { bk = k2; bp = p2; }
        }
        bk = __shfl(bk, 0);
        bp = __shfl(bp, 0);
        if (lane == 0) {
            u32 hm = ~(u32)(bk >> 32);
            u32 u = (hm & 0x80000000u) ? (hm & 0x7fffffffu) : ~hm;
            sc[wave * KDET + it] = __uint_as_float(u);
            si[wave * KDET + it] = (int)(bk & 0xFFFFFFFFu);
            keys[wave][bp] = ~0ULL;
        }
    }
    __syncthreads();
    if (wave == 0) {
        const int t = lane;
        for (int r = 0; r < KDET; ++r) {
            float bv = -INFINITY; int bp = 0x7fffffff;
            for (int i = t; i < 150; i += 64) {
                float v = sc[i];
                if (v > bv) { bv = v; bp = i; }
            }
#pragma unroll
            for (int s = 32; s > 0; s >>= 1) {
                float v2 = __shfl_down(bv, s);
                int   p2 = __shfl_down(bp, s);
                if (v2 > bv || (v2 == bv && p2 < bp)) { bv = v2; bp = p2; }
            }
            bp = __shfl(bp, 0);
            if (t == 0) {
                int cls = bp / KDET;
                int ind = si[bp];
                int n = b * KDET + r;
                clsArr[n] = cls;
                int x = ind % FW, yy = ind / FW;
                float cx = (float)x  + off2[(((long)b * 2 + 0) * FH + yy) * FW + x];
                float cy = (float)yy + off2[(((long)b * 2 + 1) * FH + yy) * FW + x];
                float w  = siz2[(((long)b * 2 + 0) * FH + yy) * FW + x];
                float h  = siz2[(((long)b * 2 + 1) * FH + yy) * FW + x];
                boxes[n * 5 + 0] = (float)b;
                boxes[n * 5 + 1] = cx - w * 0.5f;
                boxes[n * 5 + 2] = cy - h * 0.5f;
                boxes[n * 5 + 3] = cx + w * 0.5f;
                boxes[n * 5 + 4] = cy + h * 0.5f;
                sc[bp] = -INFINITY;
            }
        }
    }
}

// =====================================================================
// ROI metadata helper
// =====================================================================
#define ROI_META \
    if (tid < 14) { \
        float roi_w = fmaxf(bx2 - bx1, 1.f); \
        float X = bx1 + (roi_w / 7.f) * ((tid + 0.5f) * 0.5f); \
        vxs[tid] = (X > -1.f) && (X < (float)FW); \
        float Xc = fminf(fmaxf(X, 0.f), (float)(FW - 1)); \
        int xi = (int)floorf(Xc); \
        x0s[tid] = xi; x1s[tid] = min(xi + 1, FW - 1); lxs[tid] = Xc - (float)xi; \
    } else if (tid >= 16 && tid < 30) { \
        int i = tid - 16; \
        float roi_h = fmaxf(by2 - by1, 1.f); \
        float Y = by1 + (roi_h / 7.f) * ((i + 0.5f) * 0.5f); \
        vys[i] = (Y > -1.f) && (Y < (float)FH); \
        float Yc = fminf(fmaxf(Y, 0.f), (float)(FH - 1)); \
        int yi = (int)floorf(Yc); \
        y0s[i] = yi; y1s[i] = min(yi + 1, FH - 1); lys[i] = Yc - (float)yi; \
    } else if (tid >= 32 && tid < 46) { \
        int j = tid - 32; \
        const float* cal = par + PB_CAL + b * 12; \
        float f_u = cal[0], c_u = cal[2], t03 = cal[3]; \
        float f_v = cal[5], c_v = cal[6], t13 = cal[7]; \
        float bxc = t03 / (-f_u), byc = t13 / (-f_v); \
        const float* cr = par + PB_CRN + b * 4; \
        float crx0 = cr[0], cry0 = cr[1], crx1 = cr[2], cry1 = cr[3]; \
        float sx = crx1 - crx0, sy = cry1 - cry0; \
        float u1 = bx1 / (float)FW * sx + crx0, v1 = by1 / (float)FH * sy + cry0; \
        float u2 = bx2 / (float)FW * sx + crx0, v2 = by2 / (float)FH * sy + cry0; \
        float p1x = (u1 - c_u) / f_u + bxc, p1y = (v1 - c_v) / f_v + byc; \
        float p2x = (u2 - c_u) / f_u + bxc, p2y = (v2 - c_v) / f_v + byc; \
        if (j < 7) cxs[j] = p1x + ((float)j / 6.f) * (p2x - p1x); \
        else       cys[j - 7] = p1y + ((float)(j - 7) / 6.f) * (p2y - p1y); \
    }

// =====================================================================
// Fused ROI-align + MFMA head (bigws path): stages r_lds directly from
// transposed features (coalesced corners), then conv+BN+mean+1x1.
// =====================================================================
__global__ __launch_bounds__(256, 4)
void kHeadM2(const u16* __restrict__ featT, const float* __restrict__ boxes,
             const int* __restrict__ clsArr, const u16* __restrict__ whb,
             const float* __restrict__ par, float* __restrict__ head_out) {
    const int h = blockIdx.x, n = blockIdx.y, tid = threadIdx.x;
    const int wave = tid >> 6, lane = tid & 63;
    const int q = lane >> 4, n15 = lane & 15;
    const int ocArr[4] = {2, 2, 4, 24};
    const int offArr[4] = {0, 2, 4, 8};
    __shared__ __align__(16) u16 r_lds[9][9][104];
    __shared__ float means[256];
    __shared__ int   x0s[14], x1s[14], y0s[14], y1s[14], vxs[14], vys[14];
    __shared__ float lxs[14], lys[14], cxs[7], cys[7];

    const float bx1 = boxes[n * 5 + 1], by1 = boxes[n * 5 + 2];
    const float bx2 = boxes[n * 5 + 3], by2 = boxes[n * 5 + 4];
    const int b = (int)boxes[n * 5 + 0];
    ROI_META

    for (int i = tid; i < 9 * 9 * 104 / 8; i += 256)
        ((uint4*)r_lds)[i] = (uint4){0, 0, 0, 0};
    __syncthreads();

    const u16* fb = featT + (long)b * FH * FW * 64;
    for (int t = tid; t < CIN * 49; t += 256) {
        int c = t & 63, p = t >> 6;        // lanes: consecutive c (coalesced)
        int oy = p / 7, ox = p % 7;
        float acc = 0.f;
#pragma unroll
        for (int dy = 0; dy < 2; ++dy) {
            int sy = oy * 2 + dy;
            float ly = lys[sy]; int yA = y0s[sy], yB = y1s[sy], vy = vys[sy];
#pragma unroll
            for (int dx = 0; dx < 2; ++dx) {
                int sx = ox * 2 + dx;
                float lx = lxs[sx]; int xA = x0s[sx], xB = x1s[sx];
                float v = (1.f - ly) * (1.f - lx) * b2f(fb[((long)yA * FW + xA) * 64 + c])
                        + (1.f - ly) * lx         * b2f(fb[((long)yA * FW + xB) * 64 + c])
                        + ly * (1.f - lx)         * b2f(fb[((long)yB * FW + xA) * 64 + c])
                        + ly * lx                 * b2f(fb[((long)yB * FW + xB) * 64 + c]);
                if (!(vy && vxs[sx])) v = 0.f;
                acc += v;
            }
        }
        r_lds[oy + 1][ox + 1][c] = f2b(acc * 0.25f);
    }
    {
        int cls = clsArr[n];
        for (int t = tid; t < 5 * 49; t += 256) {
            int ch = t / 49, p = t % 49, i = p / 7, j = p % 7;
            float v;
            if (ch == 0)      v = cxs[j];
            else if (ch == 1) v = cys[i];
            else              v = (cls == ch - 2) ? 1.f : 0.f;
            r_lds[i + 1][j + 1][64 + ch] = f2b(v);
        }
    }
    __syncthreads();

    int oyA[4], oxA[4];
#pragma unroll
    for (int i = 0; i < 4; ++i) {
        int pos = i * 16 + n15; if (pos > 48) pos = 48;
        oyA[i] = pos / 7; oxA[i] = pos % 7;
    }

    f32x4 acc[4][4];
#pragma unroll
    for (int i = 0; i < 4; ++i)
#pragma unroll
        for (int t = 0; t < 4; ++t) acc[i][t] = (f32x4){0.f, 0.f, 0.f, 0.f};

#pragma unroll 1
    for (int tap = 0; tap < 9; ++tap) {
        const int ky = tap / 3, kx = tap % 3;
        const u16* wt = whb + ((long)h * 9 + tap) * 24576;
#pragma unroll
        for (int cs = 0; cs < 3; ++cs) {
            short8 afr[4], bfr[4];
#pragma unroll
            for (int i = 0; i < 4; ++i)
                afr[i] = *(const short8*)&r_lds[oyA[i] + ky][oxA[i] + kx][cs * 32 + q * 8];
#pragma unroll
            for (int t = 0; t < 4; ++t)
                bfr[t] = *(const short8*)(wt + ((cs << 8) + wave * 64 + t * 16 + n15) * 32 + q * 8);
#pragma unroll
            for (int i = 0; i < 4; ++i)
#pragma unroll
                for (int t = 0; t < 4; ++t)
                    acc[i][t] = __builtin_amdgcn_mfma_f32_16x16x32_bf16(
                        afr[i], bfr[t], acc[i][t], 0, 0, 0);
        }
    }

    const float* hb = par + PB_HD0 + h * 7456;
#pragma unroll
    for (int t = 0; t < 4; ++t) {
        int oc = wave * 64 + t * 16 + n15;
        float b1 = hb[oc], g = hb[256 + oc], be = hb[512 + oc];
        float m = hb[768 + oc], v = hb[1024 + oc];
        float scale = g / sqrtf(v + 1e-5f);
        float s = 0.f;
#pragma unroll
        for (int i = 0; i < 4; ++i)
#pragma unroll
            for (int r = 0; r < 4; ++r) {
                int pos = i * 16 + q * 4 + r;
                if (pos < 49)
                    s += fmaxf((acc[i][t][r] + b1 - m) * scale + be, 0.f);
            }
        s += __shfl_xor(s, 16);
        s += __shfl_xor(s, 32);
        if (q == 0) means[oc] = s / 49.f;
    }
    __syncthreads();

    int oc_out = ocArr[h];
    const float* w2 = hb + 1280;
    for (int k = wave; k < oc_out; k += 4) {
        float s = 0.f;
        for (int c = lane; c < 256; c += 64) s += means[c] * w2[k * 256 + c];
#pragma unroll
        for (int off = 32; off > 0; off >>= 1) s += __shfl_down(s, off);
        if (lane == 0)
            head_out[(long)n * 32 + offArr[h] + k] = s + w2[oc_out * 256 + k];
    }
}

// =====================================================================
// Fallback path (small ws): separate ROI-align + head reading roi_in
// =====================================================================
__global__ __launch_bounds__(256)
void kRoi(const void* __restrict__ feat, const int* __restrict__ flag,
          const float* __restrict__ boxes, const int* __restrict__ clsArr,
          const float* __restrict__ par, float* __restrict__ roi_in) {
    const int n = blockIdx.x, tid = threadIdx.x;
    const int bf = *flag;
    __shared__ int   x0s[14], x1s[14], y0s[14], y1s[14], vxs[14], vys[14];
    __shared__ float lxs[14], lys[14], cxs[7], cys[7];

    const float bx1 = boxes[n * 5 + 1], by1 = boxes[n * 5 + 2];
    const float bx2 = boxes[n * 5 + 3], by2 = boxes[n * 5 + 4];
    const int b = (int)boxes[n * 5 + 0];

    ROI_META
    __syncthreads();

    for (int t = tid; t < CIN * 49; t += 256) {
        int c = t / 49, p = t % 49, oy = p / 7, ox = p % 7;
        long fb = ((long)b * CIN + c) * HW;
        float acc = 0.f;
#pragma unroll
        for (int dy = 0; dy < 2; ++dy) {
            int sy = oy * 2 + dy;
            float ly = lys[sy]; int yA = y0s[sy], yB = y1s[sy], vy = vys[sy];
#pragma unroll
            for (int dx = 0; dx < 2; ++dx) {
                int sx = ox * 2 + dx;
                float lx = lxs[sx]; int xA = x0s[sx], xB = x1s[sx];
                float v = (1.f - ly) * (1.f - lx) * gload(feat, fb + yA * FW + xA, bf)
                        + (1.f - ly) * lx         * gload(feat, fb + yA * FW + xB, bf)
                        + ly * (1.f - lx)         * gload(feat, fb + yB * FW + xA, bf)
                        + ly * lx                 * gload(feat, fb + yB * FW + xB, bf);
                if (!(vy && vxs[sx])) v = 0.f;
                acc += v;
            }
        }
        roi_in[((long)n * CROI + c) * 49 + p] = acc * 0.25f;
    }
    int cls = clsArr[n];
    for (int t = tid; t < 5 * 49; t += 256) {
        int ch = t / 49, p = t % 49, i = p / 7, j = p % 7;
        float v;
        if (ch == 0)      v = cxs[j];
        else if (ch == 1) v = cys[i];
        else              v = (cls == ch - 2) ? 1.f : 0.f;
        roi_in[((long)n * CROI + 64 + ch) * 49 + p] = v;
    }
}

__global__ __launch_bounds__(256, 4)
void kHeadM(const float* __restrict__ roi_in, const u16* __restrict__ whb,
            const float* __restrict__ par, float* __restrict__ head_out) {
    const int h = blockIdx.x, n = blockIdx.y, tid = threadIdx.x;
    const int wave = tid >> 6, lane = tid & 63;
    const int q = lane >> 4, n15 = lane & 15;
    const int ocArr[4] = {2, 2, 4, 24};
    const int offArr[4] = {0, 2, 4, 8};
    __shared__ __align__(16) u16 r_lds[9][9][104];
    __shared__ float means[256];

    for (int i = tid; i < 9 * 9 * 104 / 8; i += 256)
        ((uint4*)r_lds)[i] = (uint4){0, 0, 0, 0};
    __syncthreads();
    const float* rp = roi_in + (long)n * CROI * 49;
    for (int i = tid; i < CROI * 49; i += 256) {
        int c = i / 49, p = i % 49;
        r_lds[p / 7 + 1][p % 7 + 1][c] = f2b(rp[i]);
    }
    __syncthreads();

    int oyA[4], oxA[4];
#pragma unroll
    for (int i = 0; i < 4; ++i) {
        int pos = i * 16 + n15; if (pos > 48) pos = 48;
        oyA[i] = pos / 7; oxA[i] = pos % 7;
    }

    f32x4 acc[4][4];
#pragma unroll
    for (int i = 0; i < 4; ++i)
#pragma unroll
        for (int t = 0; t < 4; ++t) acc[i][t] = (f32x4){0.f, 0.f, 0.f, 0.f};

#pragma unroll 1
    for (int tap = 0; tap < 9; ++tap) {
        const int ky = tap / 3, kx = tap % 3;
        const u16* wt = whb + ((long)h * 9 + tap) * 24576;
#pragma unroll
        for (int cs = 0; cs < 3; ++cs) {
            short8 afr[4], bfr[4];
#pragma unroll
            for (int i = 0; i < 4; ++i)
                afr[i] = *(const short8*)&r_lds[oyA[i] + ky][oxA[i] + kx][cs * 32 + q * 8];
#pragma unroll
            for (int t = 0; t < 4; ++t)
                bfr[t] = *(const short8*)(wt + ((cs << 8) + wave * 64 + t * 16 + n15) * 32 + q * 8);
#pragma unroll
            for (int i = 0; i < 4; ++i)
#pragma unroll
                for (int t = 0; t < 4; ++t)
                    acc[i][t] = __builtin_amdgcn_mfma_f32_16x16x32_bf16(
                        afr[i], bfr[t], acc[i][t], 0, 0, 0);
        }
    }

    const float* hb = par + PB_HD0 + h * 7456;
#pragma unroll
    for (int t = 0; t < 4; ++t) {
        int oc = wave * 64 + t * 16 + n15;
        float b1 = hb[oc], g = hb[256 + oc], be = hb[512 + oc];
        float m = hb[768 + oc], v = hb[1024 + oc];
        float scale = g / sqrtf(v + 1e-5f);
        float s = 0.f;
#pragma unroll
        for (int i = 0; i < 4; ++i)
#pragma unroll
            for (int r = 0; r < 4; ++r) {
                int pos = i * 16 + q * 4 + r;
                if (pos < 49)
                    s += fmaxf((acc[i][t][r] + b1 - m) * scale + be, 0.f);
            }
        s += __shfl_xor(s, 16);
        s += __shfl_xor(s, 32);
        if (q == 0) means[oc] = s / 49.f;
    }
    __syncthreads();

    int oc_out = ocArr[h];
    const float* w2 = hb + 1280;
    for (int k = wave; k < oc_out; k += 4) {
        float s = 0.f;
        for (int c = lane; c < 256; c += 64) s += means[c] * w2[k * 256 + c];
#pragma unroll
        for (int off = 32; off > 0; off >>= 1) s += __shfl_down(s, off);
        if (lane == 0)
            head_out[(long)n * 32 + offArr[h] + k] = s + w2[oc_out * 256 + k];
    }
}

// =====================================================================
// Final scalar math + small outputs
// =====================================================================
__global__ void kFinal(const float* __restrict__ head_out, const float* __restrict__ boxes,
                       const int* __restrict__ clsArr, const float* __restrict__ par,
                       void* __restrict__ out, const int* __restrict__ flag) {
    int n = blockIdx.x * 256 + threadIdx.x;
    if (n >= NROI) return;
    const int bf = *flag;
    const float* ho = head_out + (long)n * 32;
    float dep0 = ho[0], dep1 = ho[1];
    int b = (int)boxes[n * 5 + 0];
    int cls = clsArr[n];

    for (int j = 0; j < 24; ++j) gstore(out, O_HEAD + n * 24 + j, ho[8 + j], bf);
    gstore(out, O_OFF3 + n * 2 + 0, ho[2], bf);
    gstore(out, O_OFF3 + n * 2 + 1, ho[3], bf);
    gstore(out, O_S3D + n * 3 + 0, ho[4], bf);
    gstore(out, O_S3D + n * 3 + 1, ho[5], bf);
    gstore(out, O_S3D + n * 3 + 2, ho[6], bf);
    gstore(out, O_H3D + n, ho[7], bf);

    float cry0 = par[PB_CRN + b * 4 + 1], cry1 = par[PB_CRN + b * 4 + 3];
    float sy = cry1 - cry0;
    float bi2 = boxes[n * 5 + 2] / (float)FH * sy + cry0;
    float bi4 = boxes[n * 5 + 4] / (float)FH * sy + cry0;
    float box_h = fmaxf(bi4 - bi2, 1.f);
    float f_u = par[PB_CAL + b * 12 + 0];
    float size3d0 = par[PB_MSZ + cls * 3 + 0] + ho[4];
    float depth_geo = size3d0 / box_h * f_u;
    float sig = 1.f / (1.f + expf(-dep0));
    float d0 = 1.f / (sig + 1e-6f) - 1.f + depth_geo;
    float dgls = ho[7] + 2.f * (logf(f_u) - logf(box_h));
    float mx = fmaxf(dep1, dgls);
    float lse = mx + logf(expf(dep1 - mx) + expf(dgls - mx));
    gstore(out, O_DEP + n * 2 + 0, d0, bf);
    gstore(out, O_DEP + n * 2 + 1, lse, bf);
}

// =====================================================================
extern "C" void kernel_launch(void* const* d_in, const int* in_sizes, int n_in,
                              void* d_out, int out_size, void* d_ws, size_t ws_size,
                              hipStream_t stream) {
    (void)in_sizes; (void)n_in; (void)out_size;
    float* ws = (float*)d_ws;
    float* par = ws + WS_PAR;
    int* flag = (int*)(ws + WS_FLAG);
    u16* wb16 = (u16*)(ws + WS_WB16);
    u16* whb  = (u16*)(ws + WS_W1H);
    u16* featT = (u16*)(ws + WS_FEATT);
    const void* feat = d_in[0];
    const bool bigws = ws_size >= (size_t)WS_END * 4;

    WPtrs WP;
    WP.bw[0] = d_in[4]; WP.bw[1] = d_in[8]; WP.bw[2] = d_in[12];
    WP.hw[0] = d_in[16]; WP.hw[1] = d_in[24]; WP.hw[2] = d_in[32]; WP.hw[3] = d_in[40];

    Segs SG; int si = 0;
    auto add = [&](const void* s, int n, int dst) {
        SG.s[si].src = s; SG.s[si].n = n; SG.s[si].dst = dst; ++si;
    };
    add(d_in[1], 96, PB_CAL); add(d_in[2], 32, PB_CRN); add(d_in[3], 9, PB_MSZ);
    const int ocb[3] = {3, 2, 2};
    for (int b = 0; b < 3; ++b) {
        int base = PB_BR0 + b * 1040;
        int i0 = 4 + 4 * b;
        add(d_in[i0 + 1], 256, base);
        add(d_in[i0 + 2], ocb[b] * 256, base + 256);
        add(d_in[i0 + 3], ocb[b], base + 256 + ocb[b] * 256);
    }
    const int och[4] = {2, 2, 4, 24};
    for (int h = 0; h < 4; ++h) {
        int base = PB_HD0 + h * 7456;
        int i0 = 16 + 8 * h;
        add(d_in[i0 + 1], 256, base);
        add(d_in[i0 + 2], 256, base + 256);
        add(d_in[i0 + 3], 256, base + 512);
        add(d_in[i0 + 4], 256, base + 768);
        add(d_in[i0 + 5], 256, base + 1024);
        add(d_in[i0 + 6], och[h] * 256, base + 1280);
        add(d_in[i0 + 7], och[h], base + 1280 + och[h] * 256);
    }
    SG.cnt = si;

    kPrepWP<<<5760 + 40, 256, 0, stream>>>(WP, SG, feat, flag,
                                           ws + WS_W1T, wb16, whb, par);

    // mega dispatch: strip first (z==0) so it overlaps conv (z=1..8);
    // conv role also emits featT (transpose role removed)
    kBranch3M<<<dim3(5, 48, 9), 512, 0, stream>>>(
        feat, flag, wb16, par + PB_BR0, ws + WS_W1T, d_out, ws, bigws ? 1 : 0);

    kNmsTopA<<<dim3(24, NCHUNK), 256, 0, stream>>>(ws + WS_HEAT, ws + WS_NH);
    kTopBC<<<8, 192, 0, stream>>>(ws + WS_NH, ws + WS_OFF2, ws + WS_SIZ2,
                                  ws + WS_BOX, (int*)(ws + WS_CLS));
    if (bigws) {
        kHeadM2<<<dim3(4, NROI), 256, 0, stream>>>(featT, ws + WS_BOX,
                                                   (int*)(ws + WS_CLS), whb, par,
                                                   ws + WS_HOUT);
    } else {
        kRoi<<<400, 256, 0, stream>>>(feat, flag, ws + WS_BOX, (int*)(ws + WS_CLS),
                                      par, ws + WS_ROI);
        kHeadM<<<dim3(4, NROI), 256, 0, stream>>>(ws + WS_ROI, whb, par, ws + WS_HOUT);
    }
    kFinal<<<2, 256, 0, stream>>>(ws + WS_HOUT, ws + WS_BOX, (int*)(ws + WS_CLS),
                                  par, d_out, flag);
}

// Round 3
// 755.037 us; speedup vs baseline: 1.1141x; 1.1141x over previous
//
#include <hip/hip_runtime.h>
#include <math.h>

typedef unsigned short u16;
typedef unsigned int   u32;
typedef unsigned long long u64;
typedef __attribute__((ext_vector_type(8))) short short8;   // 8 bf16 (4 VGPR)
typedef __attribute__((ext_vector_type(4))) float f32x4;    // MFMA acc

// ---------- dtype helpers ----------
__device__ __forceinline__ float b2f(u16 v) { return __uint_as_float(((u32)v) << 16); }
__device__ __forceinline__ u16 f2b(float f) {
    u32 u = __float_as_uint(f);
    u32 r = (u + 0x7FFFu + ((u >> 16) & 1u)) >> 16;   // RNE
    return (u16)r;
}
__device__ __forceinline__ float gload(const void* p, long i, int bf) {
    return bf ? b2f(((const u16*)p)[i]) : ((const float*)p)[i];
}
__device__ __forceinline__ void gstore(void* p, long i, float v, int bf) {
    if (bf) ((u16*)p)[i] = f2b(v);
    else    ((float*)p)[i] = v;
}

// top-k key: smallest key = (largest value, then smallest index)
__device__ __forceinline__ u64 packKey(float v, int idx) {
    u32 u = __float_as_uint(v);
    u32 m = (u & 0x80000000u) ? ~u : (u | 0x80000000u);   // monotone float->uint
    return ((u64)(~m) << 32) | (u32)idx;
}

// per-block dtype-flag recompute (512 u16 probe of feat)
__device__ int blockFlag(const void* feat) {
    __shared__ int fcnt;
    if (threadIdx.x == 0) fcnt = 0;
    __syncthreads();
    int sane = 0;
    for (int i = threadIdx.x; i < 512; i += blockDim.x) {
        u16 v = ((const u16*)feat)[i];
        float f = b2f(v);
        u32 e = (v >> 7) & 0xFF;
        float a = fabsf(f);
        sane += (e != 0xFF) && (f == 0.f || (a >= 1e-8f && a <= 1e4f));
    }
    atomicAdd(&fcnt, sane);
    __syncthreads();
    return fcnt >= 480;
}

// ---------- problem constants ----------
#define BATCH 8
#define CIN   64
#define FH    96
#define FW    320
#define KDET  50
#define NROI  400
#define CROI  69
#define HW    (FH*FW)
#define CHUNK 1920
#define NCHUNK 16

// ---------- workspace layout (float offsets) ----------
#define WS_HEAT 0L
#define WS_OFF2 737280L
#define WS_SIZ2 1228800L
#define WS_NH   1720320L
#define WS_CLS  2460000L
#define WS_BOX  2460400L
#define WS_ROI  2462400L
#define WS_HOUT 3814800L
#define WS_W1T  3827600L     // 147456 f32: hm conv1 [k=576][c=256] (exact strip)
#define WS_WB16 3975056L     // u16: 3 branches * [9][2][256][32] bf16 (lane-coalesced)
#define WS_W1H  4269968L     // u16: 4 heads * [9][3][256][32] bf16
#define WS_PAR  4905872L     // packed f32 params
#define WS_FLAG 4938960L     // int dtype flag
#define WS_FEATT 4938964L    // u16: [8][96][320][64] bf16 transposed features
#define WS_END  (WS_FEATT + 7864320L)

// param block sub-offsets
#define PB_CAL 0
#define PB_CRN 96
#define PB_MSZ 128
#define PB_BR0 144          // stride 1040: b1@0, w2@256 ([k][n]), b2@256+OC*256
#define PB_HD0 3264         // stride 7456

// ---------- output layout (element offsets) ----------
#define O_HEAT 0L
#define O_OFF2 737280L
#define O_SIZ2 1228800L
#define O_HEAD 1720320L
#define O_DEP  1729920L
#define O_OFF3 1730720L
#define O_S3D  1731520L
#define O_H3D  1732720L

// =====================================================================
// Fused prep: weights + params + flag
// =====================================================================
struct WPtrs { const void* bw[3]; const void* hw[4]; };
struct Seg { const void* src; int n; int dst; };
struct Segs { Seg s[40]; int cnt; };

__global__ void kPrepWP(WPtrs P, Segs S, const void* __restrict__ feat,
                        int* __restrict__ flag, float* __restrict__ w1t,
                        u16* __restrict__ wb16, u16* __restrict__ whb,
                        float* __restrict__ par) {
    const int bf = blockFlag(feat);
    if (blockIdx.x == 0 && threadIdx.x == 0) *flag = bf;
    if (blockIdx.x < 5760) {
        int idx = blockIdx.x * 256 + threadIdx.x;
        if (idx < 147456) {
            int k = idx >> 8, c = idx & 255;
            w1t[idx] = gload(P.bw[0], (long)c * 576 + k, bf);
        } else if (idx < 589824) {
            int j = idx - 147456;
            int br = j / 147456, rem = j % 147456;
            int tap = rem / 16384;
            int r2 = rem & 16383;
            int s = r2 >> 13;
            int n = (r2 >> 5) & 255;
            int c5 = r2 & 31;
            int ci = s * 32 + c5;
            wb16[j] = f2b(gload(P.bw[br], (long)n * 576 + ci * 9 + tap, bf));
        } else {
            int j = idx - 589824;               // < 884736
            int h = j / 221184, rem = j % 221184;
            int tap = rem / 24576, rem2 = rem % 24576;
            int cs = rem2 / 8192, rem3 = rem2 % 8192;
            int oc = rem3 >> 5, jj = rem3 & 31;
            int ci = cs * 32 + jj;
            u16 val = 0;
            if (ci < CROI) val = f2b(gload(P.hw[h], (long)oc * 621 + ci * 9 + tap, bf));
            whb[j] = val;
        }
    } else {
        int sidx = blockIdx.x - 5760;
        if (sidx < S.cnt) {
            Seg sg = S.s[sidx];
            for (int i = threadIdx.x; i < sg.n; i += 256)
                par[sg.dst + i] = gload(sg.src, i, bf);
        }
    }
}

// =====================================================================
// Mega branch dispatch: grid (5, 48, 9)
//   z==0 : exact f32 strip role (heat rows 0..2) -- dispatched FIRST so
//          its long blocks overlap the conv wave instead of tailing
//   z>=1 : MFMA conv role (b=z-1); heat stores skip rows 0..2; also
//          emits featT directly from its LDS staging tile (doT)
// =====================================================================
union MLds {
    struct { u16 a[4][68][72]; float red[3][8][64][3]; } c;   // red per-branch
    struct {
        float in[4][3][36];
        union { float w[36 * 256]; float part[32 * 3 * 32]; } u;
    } s;
};

__global__ __launch_bounds__(512, 4)
void kBranch3M(const void* __restrict__ feat, const int* __restrict__ flag,
               const u16* __restrict__ wbAll,   // 3 * [9][2][256][32] bf16
               const float* __restrict__ bpAll, // par + PB_BR0, stride 1040
               const float* __restrict__ w1t,   // strip weights f32
               void* __restrict__ outb, float* __restrict__ wsbase, int doT) {
    __shared__ __align__(16) MLds L;

    const long obase[3] = {O_HEAT, O_OFF2, O_SIZ2};
    const long wfs[3]   = {WS_HEAT, WS_OFF2, WS_SIZ2};

    const int bfl = *flag;
    const int tid = threadIdx.x;

    if (blockIdx.z == 0) {
        // ================= STRIP ROLE (exact f32, rows 0..2) ==========
        const int sidx = blockIdx.y * 5 + blockIdx.x;   // 0..239
        const int x0 = (sidx % 10) * 32;
        const int srem = sidx / 10;
        const int y = srem % 3;
        const int b = srem / 3;
        const float* bp = bpAll;                        // heat branch params
        const int OC = 3;
        const int xg = tid & 7, cg = tid >> 3;
        const int c0 = (cg & 31) * 8;

        float acc[8][4];
#pragma unroll
        for (int i = 0; i < 8; ++i)
#pragma unroll
            for (int j = 0; j < 4; ++j) acc[i][j] = 0.f;

        for (int chunk = 0; chunk < 16; ++chunk) {
            const int ci0 = chunk * 4;
            __syncthreads();
            for (int i = tid; i < 4 * 3 * 36; i += 512) {
                int xx = i % 36, t2 = i / 36;
                int r = t2 % 3, ci = t2 / 3;
                int gx = x0 - 1 + xx, gy = y - 1 + r;
                float v = 0.f;
                if (gx >= 0 && gx < FW && gy >= 0 && gy < FH)
                    v = gload(feat, ((long)(b * CIN + ci0 + ci) * FH + gy) * FW + gx, bfl);
                L.s.in[ci][r][xx] = v;
            }
            {
                const float4* src = (const float4*)(w1t + (long)ci0 * 9 * 256);
                float4* dst = (float4*)L.s.u.w;
                for (int i = tid; i < 36 * 256 / 4; i += 512) dst[i] = src[i];
            }
            __syncthreads();
            if (tid < 256) {
#pragma unroll
                for (int ci = 0; ci < 4; ++ci) {
#pragma unroll
                    for (int ky = 0; ky < 3; ++ky) {
                        const float* rowp = &L.s.in[ci][ky][xg * 4];
                        float inv[6];
                        *(float4*)&inv[0] = *(const float4*)&rowp[0];
                        *(float2*)&inv[4] = *(const float2*)&rowp[4];
#pragma unroll
                        for (int kx = 0; kx < 3; ++kx) {
                            const float* wp = &L.s.u.w[(ci * 9 + ky * 3 + kx) * 256 + c0];
                            float wv[8];
                            *(float4*)&wv[0] = *(const float4*)&wp[0];
                            *(float4*)&wv[4] = *(const float4*)&wp[4];
#pragma unroll
                            for (int cc = 0; cc < 8; ++cc)
#pragma unroll
                                for (int xx = 0; xx < 4; ++xx)
                                    acc[cc][xx] = fmaf(wv[cc], inv[xx + kx], acc[cc][xx]);
                        }
                    }
                }
            }
        }

        if (tid < 256) {
#pragma unroll
            for (int cc = 0; cc < 8; ++cc) {
                float b1v = bp[c0 + cc];
#pragma unroll
                for (int xx = 0; xx < 4; ++xx)
                    acc[cc][xx] = fmaxf(acc[cc][xx] + b1v, 0.f);
            }
        }
        __syncthreads();
        if (tid < 256) {
#pragma unroll
            for (int k = 0; k < OC; ++k) {
                float p[4];
#pragma unroll
                for (int xx = 0; xx < 4; ++xx) p[xx] = 0.f;
#pragma unroll
                for (int cc = 0; cc < 8; ++cc) {
                    float wv = bp[256 + k * 256 + c0 + cc];
#pragma unroll
                    for (int xx = 0; xx < 4; ++xx) p[xx] = fmaf(acc[cc][xx], wv, p[xx]);
                }
#pragma unroll
                for (int xx = 0; xx < 4; ++xx)
                    L.s.u.part[((cg & 31) * OC + k) * 32 + xg * 4 + xx] = p[xx];
            }
        }
        __syncthreads();
        float* outf = wsbase + WS_HEAT;
        for (int t = tid; t < OC * 32; t += 512) {
            int k = t >> 5, xx = t & 31;
            float s = bp[256 + OC * 256 + k];
#pragma unroll 8
            for (int g = 0; g < 32; ++g) s += L.s.u.part[(g * OC + k) * 32 + xx];
            long o = (((long)b * OC + k) * FH + y) * FW + x0 + xx;
            gstore(outb, O_HEAT + o, s, bfl);
            outf[o] = s;
        }
        return;
    }

    // ==================== CONV ROLE (MFMA) ============================
    const int wave = tid >> 6, lane = tid & 63;
    const int q = lane >> 4, n15 = lane & 15;
    const int mg = wave >> 2, ng = wave & 3;
    const int x0 = blockIdx.x * 64, y0 = blockIdx.y * 2;
    const int b = blockIdx.z - 1;

    // staging with all 512 threads (round-0 used 256, idling 4 waves)
    {
        const int ci = tid & 63, rr = (tid >> 6) & 3, hf = tid >> 8;
        const int gy = y0 - 1 + rr;
        if (gy < 0 || gy >= FH) {
            for (int xi = hf * 33; xi < hf * 33 + 33; ++xi) L.c.a[rr][xi][ci] = 0;
        } else if (bfl) {
            const u16* rp = (const u16*)feat + ((long)((b << 6) | ci) * FH + gy) * FW;
            for (int j = hf * 5; j < hf * 5 + 5; ++j) {
                int xs0 = x0 - 8 + j * 8;
                u16 tmp[8];
                if (xs0 >= 0 && xs0 <= FW - 8)
                    *(uint4*)tmp = *(const uint4*)(rp + xs0);
                else
                    for (int e = 0; e < 8; ++e) {
                        int gx = xs0 + e;
                        tmp[e] = (gx >= 0 && gx < FW) ? rp[gx] : (u16)0;
                    }
                for (int e = 0; e < 8; ++e) {
                    int xi = xs0 + e - x0 + 1;
                    if (xi >= 0 && xi < 66) L.c.a[rr][xi][ci] = tmp[e];
                }
            }
        } else {
            const float* rp = (const float*)feat + ((long)((b << 6) | ci) * FH + gy) * FW;
            for (int j = hf * 9; j < hf * 9 + 9; ++j) {
                int xs0 = x0 - 4 + j * 4;
                float tmp[4];
                if (xs0 >= 0 && xs0 <= FW - 4)
                    *(float4*)tmp = *(const float4*)(rp + xs0);
                else
                    for (int e = 0; e < 4; ++e) {
                        int gx = xs0 + e;
                        tmp[e] = (gx >= 0 && gx < FW) ? rp[gx] : 0.f;
                    }
                for (int e = 0; e < 4; ++e) {
                    int xi = xs0 + e - x0 + 1;
                    if (xi >= 0 && xi < 66) L.c.a[rr][xi][ci] = f2b(tmp[e]);
                }
            }
        }
    }
    __syncthreads();   // a_lds visible; read-only from here on

    // ---- emit transposed features directly from the staged LDS tile ----
    if (doT) {
        u16* featT = (u16*)(wsbase + WS_FEATT);
        for (int i = tid; i < 1024; i += 512) {           // 2 rows * 64 x * 8 c8
            int c8 = i & 7, x = (i >> 3) & 63, r = i >> 9;
            uint4 v = *(const uint4*)&L.c.a[1 + r][1 + x][c8 * 8];
            *(uint4*)(featT + (((long)b * FH + y0 + r) * FW + x0 + x) * 64 + c8 * 8) = v;
        }
    }

    // ---- 3 branches, barrier-free (per-branch red buffers); stores
    //      deferred behind ONE barrier so MFMA/epilogue phases overlap
#pragma unroll 1
    for (int br = 0; br < 3; ++br) {
        const u16* wpt = wbAll + br * 147456;
        const float* bp = bpAll + br * 1040;

        f32x4 acc[4][4];
#pragma unroll
        for (int i = 0; i < 4; ++i)
#pragma unroll
            for (int t = 0; t < 4; ++t) acc[i][t] = (f32x4){0.f, 0.f, 0.f, 0.f};

#pragma unroll 1
        for (int tap = 0; tap < 9; ++tap) {
            const int ky = tap / 3, kx = tap % 3;
#pragma unroll
            for (int s = 0; s < 2; ++s) {
                const u16* wks = wpt + (tap * 2 + s) * 8192;
                short8 bfr[4];
#pragma unroll
                for (int t = 0; t < 4; ++t)
                    bfr[t] = *(const short8*)(wks + (ng * 64 + t * 16 + n15) * 32 + q * 8);
                short8 afr[4];
#pragma unroll
                for (int i = 0; i < 4; ++i)
                    afr[i] = *(const short8*)&L.c.a[mg + ky][i * 16 + n15 + kx][s * 32 + q * 8];
#pragma unroll
                for (int i = 0; i < 4; ++i)
#pragma unroll
                    for (int t = 0; t < 4; ++t)
                        acc[i][t] = __builtin_amdgcn_mfma_f32_16x16x32_bf16(
                            afr[i], bfr[t], acc[i][t], 0, 0, 0);
            }
        }

        float b1v[4], w2v[3][4];
#pragma unroll
        for (int t = 0; t < 4; ++t) {
            int n = ng * 64 + t * 16 + n15;
            b1v[t] = bp[n];
#pragma unroll
            for (int k = 0; k < 3; ++k) w2v[k][t] = bp[256 + k * 256 + n];
        }
#pragma unroll
        for (int i = 0; i < 4; ++i) {
#pragma unroll
            for (int r = 0; r < 4; ++r) {
                float pk[3] = {0.f, 0.f, 0.f};
#pragma unroll
                for (int t = 0; t < 4; ++t) {
                    float h = fmaxf(acc[i][t][r] + b1v[t], 0.f);
#pragma unroll
                    for (int k = 0; k < 3; ++k) pk[k] = fmaf(h, w2v[k][t], pk[k]);
                }
#pragma unroll
                for (int k = 0; k < 3; ++k) {
                    pk[k] += __shfl_xor(pk[k], 1);
                    pk[k] += __shfl_xor(pk[k], 2);
                    pk[k] += __shfl_xor(pk[k], 4);
                    pk[k] += __shfl_xor(pk[k], 8);
                }
                if (n15 == 0) {
                    int ml = i * 16 + q * 4 + r;
#pragma unroll
                    for (int k = 0; k < 3; ++k) L.c.red[br][wave][ml][k] = pk[k];
                }
            }
        }
        // no barrier: each wave owns red[br][wave]; readers wait below
    }

    __syncthreads();   // all red[0..2] complete

#pragma unroll 1
    for (int br = 0; br < 3; ++br) {
        const int oc = (br == 0) ? 3 : 2;
        const float* bp = bpAll + br * 1040;
        float* outf = wsbase + wfs[br];
        for (int t2 = tid; t2 < oc * 128; t2 += 512) {
            int k = t2 >> 7, m = t2 & 127;
            int row = m >> 6, x = m & 63;
            int mg2 = m >> 6, ml = m & 63;
            float s = bp[256 + oc * 256 + k];
#pragma unroll
            for (int w = 0; w < 4; ++w) s += L.c.red[br][mg2 * 4 + w][ml][k];
            int grow = y0 + row;
            if (br == 0 && grow < 3) continue;    // strip role owns heat rows 0..2
            long o = (((long)b * oc + k) * FH + grow) * FW + x0 + x;
            gstore(outb, obase[br] + o, s, bfl);
            outf[o] = s;
        }
    }
}

// =====================================================================
// Fused NMS + top-k stage A (4-wave hierarchical extraction)
// =====================================================================
__global__ __launch_bounds__(256)
void kNmsTopA(const float* __restrict__ heat, float* __restrict__ nh) {
    __shared__ float hrow[8][320];
    __shared__ u64 keys[CHUNK];
    __shared__ u64 sub[4][KDET];
    const int bc = blockIdx.x, ch = blockIdx.y;
    const int tid = threadIdx.x;
    const int wave = tid >> 6, lane = tid & 63;
    const int r0 = ch * 6;
    const float* hp = heat + (long)bc * HW;

    for (int i = tid; i < 8 * 320; i += 256) {
        int rr = i / 320, x = i % 320;
        int gy = r0 - 1 + rr;
        hrow[rr][x] = (gy >= 0 && gy < FH) ? hp[(long)gy * FW + x] : -INFINITY;
    }
    __syncthreads();
    for (int i = tid; i < CHUNK; i += 256) {
        int ry = i / 320, x = i % 320;
        float v = hrow[ry + 1][x];
        float m = v;
        int xm = max(x - 1, 0), xp = min(x + 1, FW - 1);
#pragma unroll
        for (int dy = 0; dy < 3; ++dy) {
            m = fmaxf(m, hrow[ry + dy][xm]);
            m = fmaxf(m, hrow[ry + dy][x]);
            m = fmaxf(m, hrow[ry + dy][xp]);
        }
        float nv = (v == m) ? v : 0.f;
        keys[i] = packKey(nv, ch * CHUNK + i);
    }
    __syncthreads();
    // each wave: top-50 of its 480-element sub-chunk
    {
        u64* kw = keys + wave * 480;
        for (int it = 0; it < KDET; ++it) {
            u64 bk = ~0ULL; int bp = 0;
            for (int i = lane; i < 480; i += 64) {
                u64 k = kw[i];
                if (k < bk) { bk = k; bp = i; }
            }
#pragma unroll
            for (int s = 32; s > 0; s >>= 1) {
                u64 k2 = __shfl_down(bk, s);
                int p2 = __shfl_down(bp, s);
                if (k2 < bk) { bk = k2; bp = p2; }
            }
            bk = __shfl(bk, 0);
            bp = __shfl(bp, 0);
            if (lane == 0) {
                sub[wave][it] = bk;
                kw[bp] = ~0ULL;
            }
        }
    }
    __syncthreads();
    // wave 0: merge 4x50 -> chunk top-50
    if (wave == 0) {
        u64* outp = (u64*)(nh + (long)bc * HW + (long)ch * CHUNK);
        u64* sp = &sub[0][0];
        for (int it = 0; it < KDET; ++it) {
            u64 bk = ~0ULL; int bp = 0;
            for (int i = lane; i < 4 * KDET; i += 64) {
                u64 k = sp[i];
                if (k < bk) { bk = k; bp = i; }
            }
#pragma unroll
            for (int s = 32; s > 0; s >>= 1) {
                u64 k2 = __shfl_down(bk, s);
                int p2 = __shfl_down(bp, s);
                if (k2 < bk) { bk = k2; bp = p2; }
            }
            bk = __shfl(bk, 0);
            bp = __shfl(bp, 0);
            if (lane == 0) {
                outp[it] = bk;
                sp[bp] = ~0ULL;
            }
        }
    }
}

// =====================================================================
// Fused top-k stage B + stage 2 + boxes
// =====================================================================
__global__ __launch_bounds__(192)
void kTopBC(const float* __restrict__ nh, const float* __restrict__ off2,
            const float* __restrict__ siz2, float* __restrict__ boxes,
            int* __restrict__ clsArr) {
    __shared__ u64 keys[3][NCHUNK * KDET];
    __shared__ float sc[150];
    __shared__ int   si[150];
    const int b = blockIdx.x, tid = threadIdx.x;
    const int wave = tid >> 6, lane = tid & 63;
    const int bc = b * 3 + wave;

    for (int ch = 0; ch < NCHUNK; ++ch) {
        const u64* src = (const u64*)(nh + (long)bc * HW + (long)ch * CHUNK);
        if (lane < KDET) keys[wave][ch * KDET + lane] = src[lane];
    }
    __syncthreads();
    for (int it = 0; it < KDET; ++it) {
        u64 bk = ~0ULL; int bp = 0;
        for (int i = lane; i < NCHUNK * KDET; i += 64) {
            u64 k = keys[wave][i];
            if (k < bk) { bk = k; bp = i; }
        }
#pragma unroll
        for (int s = 32; s > 0; s >>= 1) {
            u64 k2 = __shfl_down(bk, s);
            int p2 = __shfl_down(bp, s);
            if (k2 < bk) { bk = k2; bp = p2; }
        }
        bk = __shfl(bk, 0);
        bp = __shfl(bp, 0);
        if (lane == 0) {
            u32 hm = ~(u32)(bk >> 32);
            u32 u = (hm & 0x80000000u) ? (hm & 0x7fffffffu) : ~hm;
            sc[wave * KDET + it] = __uint_as_float(u);
            si[wave * KDET + it] = (int)(bk & 0xFFFFFFFFu);
            keys[wave][bp] = ~0ULL;
        }
    }
    __syncthreads();
    if (wave == 0) {
        const int t = lane;
        for (int r = 0; r < KDET; ++r) {
            float bv = -INFINITY; int bp = 0x7fffffff;
            for (int i = t; i < 150; i += 64) {
                float v = sc[i];
                if (v > bv) { bv = v; bp = i; }
            }
#pragma unroll
            for (int s = 32; s > 0; s >>= 1) {
                float v2 = __shfl_down(bv, s);
                int   p2 = __shfl_down(bp, s);
                if (v2 > bv || (v2 == bv && p2 < bp)) { bv = v2; bp = p2; }
            }
            bp = __shfl(bp, 0);
            if (t == 0) {
                int cls = bp / KDET;
                int ind = si[bp];
                int n = b * KDET + r;
                clsArr[n] = cls;
                int x = ind % FW, yy = ind / FW;
                float cx = (float)x  + off2[(((long)b * 2 + 0) * FH + yy) * FW + x];
                float cy = (float)yy + off2[(((long)b * 2 + 1) * FH + yy) * FW + x];
                float w  = siz2[(((long)b * 2 + 0) * FH + yy) * FW + x];
                float h  = siz2[(((long)b * 2 + 1) * FH + yy) * FW + x];
                boxes[n * 5 + 0] = (float)b;
                boxes[n * 5 + 1] = cx - w * 0.5f;
                boxes[n * 5 + 2] = cy - h * 0.5f;
                boxes[n * 5 + 3] = cx + w * 0.5f;
                boxes[n * 5 + 4] = cy + h * 0.5f;
                sc[bp] = -INFINITY;
            }
        }
    }
}

// =====================================================================
// ROI metadata helper
// =====================================================================
#define ROI_META \
    if (tid < 14) { \
        float roi_w = fmaxf(bx2 - bx1, 1.f); \
        float X = bx1 + (roi_w / 7.f) * ((tid + 0.5f) * 0.5f); \
        vxs[tid] = (X > -1.f) && (X < (float)FW); \
        float Xc = fminf(fmaxf(X, 0.f), (float)(FW - 1)); \
        int xi = (int)floorf(Xc); \
        x0s[tid] = xi; x1s[tid] = min(xi + 1, FW - 1); lxs[tid] = Xc - (float)xi; \
    } else if (tid >= 16 && tid < 30) { \
        int i = tid - 16; \
        float roi_h = fmaxf(by2 - by1, 1.f); \
        float Y = by1 + (roi_h / 7.f) * ((i + 0.5f) * 0.5f); \
        vys[i] = (Y > -1.f) && (Y < (float)FH); \
        float Yc = fminf(fmaxf(Y, 0.f), (float)(FH - 1)); \
        int yi = (int)floorf(Yc); \
        y0s[i] = yi; y1s[i] = min(yi + 1, FH - 1); lys[i] = Yc - (float)yi; \
    } else if (tid >= 32 && tid < 46) { \
        int j = tid - 32; \
        const float* cal = par + PB_CAL + b * 12; \
        float f_u = cal[0], c_u = cal[2], t03 = cal[3]; \
        float f_v = cal[5], c_v = cal[6], t13 = cal[7]; \
        float bxc = t03 / (-f_u), byc = t13 / (-f_v); \
        const float* cr = par + PB_CRN + b * 4; \
        float crx0 = cr[0], cry0 = cr[1], crx1 = cr[2], cry1 = cr[3]; \
        float sx = crx1 - crx0, sy = cry1 - cry0; \
        float u1 = bx1 / (float)FW * sx + crx0, v1 = by1 / (float)FH * sy + cry0; \
        float u2 = bx2 / (float)FW * sx + crx0, v2 = by2 / (float)FH * sy + cry0; \
        float p1x = (u1 - c_u) / f_u + bxc, p1y = (v1 - c_v) / f_v + byc; \
        float p2x = (u2 - c_u) / f_u + bxc, p2y = (v2 - c_v) / f_v + byc; \
        if (j < 7) cxs[j] = p1x + ((float)j / 6.f) * (p2x - p1x); \
        else       cys[j - 7] = p1y + ((float)(j - 7) / 6.f) * (p2y - p1y); \
    }

// =====================================================================
// Fused ROI-align + MFMA head (bigws path): stages r_lds directly from
// transposed features (coalesced corners), then conv+BN+mean+1x1.
// =====================================================================
__global__ __launch_bounds__(256, 4)
void kHeadM2(const u16* __restrict__ featT, const float* __restrict__ boxes,
             const int* __restrict__ clsArr, const u16* __restrict__ whb,
             const float* __restrict__ par, float* __restrict__ head_out) {
    const int h = blockIdx.x, n = blockIdx.y, tid = threadIdx.x;
    const int wave = tid >> 6, lane = tid & 63;
    const int q = lane >> 4, n15 = lane & 15;
    const int ocArr[4] = {2, 2, 4, 24};
    const int offArr[4] = {0, 2, 4, 8};
    __shared__ __align__(16) u16 r_lds[9][9][104];
    __shared__ float means[256];
    __shared__ int   x0s[14], x1s[14], y0s[14], y1s[14], vxs[14], vys[14];
    __shared__ float lxs[14], lys[14], cxs[7], cys[7];

    const float bx1 = boxes[n * 5 + 1], by1 = boxes[n * 5 + 2];
    const float bx2 = boxes[n * 5 + 3], by2 = boxes[n * 5 + 4];
    const int b = (int)boxes[n * 5 + 0];
    ROI_META

    for (int i = tid; i < 9 * 9 * 104 / 8; i += 256)
        ((uint4*)r_lds)[i] = (uint4){0, 0, 0, 0};
    __syncthreads();

    const u16* fb = featT + (long)b * FH * FW * 64;
    for (int t = tid; t < CIN * 49; t += 256) {
        int c = t & 63, p = t >> 6;        // lanes: consecutive c (coalesced)
        int oy = p / 7, ox = p % 7;
        float acc = 0.f;
#pragma unroll
        for (int dy = 0; dy < 2; ++dy) {
            int sy = oy * 2 + dy;
            float ly = lys[sy]; int yA = y0s[sy], yB = y1s[sy], vy = vys[sy];
#pragma unroll
            for (int dx = 0; dx < 2; ++dx) {
                int sx = ox * 2 + dx;
                float lx = lxs[sx]; int xA = x0s[sx], xB = x1s[sx];
                float v = (1.f - ly) * (1.f - lx) * b2f(fb[((long)yA * FW + xA) * 64 + c])
                        + (1.f - ly) * lx         * b2f(fb[((long)yA * FW + xB) * 64 + c])
                        + ly * (1.f - lx)         * b2f(fb[((long)yB * FW + xA) * 64 + c])
                        + ly * lx                 * b2f(fb[((long)yB * FW + xB) * 64 + c]);
                if (!(vy && vxs[sx])) v = 0.f;
                acc += v;
            }
        }
        r_lds[oy + 1][ox + 1][c] = f2b(acc * 0.25f);
    }
    {
        int cls = clsArr[n];
        for (int t = tid; t < 5 * 49; t += 256) {
            int ch = t / 49, p = t % 49, i = p / 7, j = p % 7;
            float v;
            if (ch == 0)      v = cxs[j];
            else if (ch == 1) v = cys[i];
            else              v = (cls == ch - 2) ? 1.f : 0.f;
            r_lds[i + 1][j + 1][64 + ch] = f2b(v);
        }
    }
    __syncthreads();

    int oyA[4], oxA[4];
#pragma unroll
    for (int i = 0; i < 4; ++i) {
        int pos = i * 16 + n15; if (pos > 48) pos = 48;
        oyA[i] = pos / 7; oxA[i] = pos % 7;
    }

    f32x4 acc[4][4];
#pragma unroll
    for (int i = 0; i < 4; ++i)
#pragma unroll
        for (int t = 0; t < 4; ++t) acc[i][t] = (f32x4){0.f, 0.f, 0.f, 0.f};

#pragma unroll 1
    for (int tap = 0; tap < 9; ++tap) {
        const int ky = tap / 3, kx = tap % 3;
        const u16* wt = whb + ((long)h * 9 + tap) * 24576;
#pragma unroll
        for (int cs = 0; cs < 3; ++cs) {
            short8 afr[4], bfr[4];
#pragma unroll
            for (int i = 0; i < 4; ++i)
                afr[i] = *(const short8*)&r_lds[oyA[i] + ky][oxA[i] + kx][cs * 32 + q * 8];
#pragma unroll
            for (int t = 0; t < 4; ++t)
                bfr[t] = *(const short8*)(wt + ((cs << 8) + wave * 64 + t * 16 + n15) * 32 + q * 8);
#pragma unroll
            for (int i = 0; i < 4; ++i)
#pragma unroll
                for (int t = 0; t < 4; ++t)
                    acc[i][t] = __builtin_amdgcn_mfma_f32_16x16x32_bf16(
                        afr[i], bfr[t], acc[i][t], 0, 0, 0);
        }
    }

    const float* hb = par + PB_HD0 + h * 7456;
#pragma unroll
    for (int t = 0; t < 4; ++t) {
        int oc = wave * 64 + t * 16 + n15;
        float b1 = hb[oc], g = hb[256 + oc], be = hb[512 + oc];
        float m = hb[768 + oc], v = hb[1024 + oc];
        float scale = g / sqrtf(v + 1e-5f);
        float s = 0.f;
#pragma unroll
        for (int i = 0; i < 4; ++i)
#pragma unroll
            for (int r = 0; r < 4; ++r) {
                int pos = i * 16 + q * 4 + r;
                if (pos < 49)
                    s += fmaxf((acc[i][t][r] + b1 - m) * scale + be, 0.f);
            }
        s += __shfl_xor(s, 16);
        s += __shfl_xor(s, 32);
        if (q == 0) means[oc] = s / 49.f;
    }
    __syncthreads();

    int oc_out = ocArr[h];
    const float* w2 = hb + 1280;
    for (int k = wave; k < oc_out; k += 4) {
        float s = 0.f;
        for (int c = lane; c < 256; c += 64) s += means[c] * w2[k * 256 + c];
#pragma unroll
        for (int off = 32; off > 0; off >>= 1) s += __shfl_down(s, off);
        if (lane == 0)
            head_out[(long)n * 32 + offArr[h] + k] = s + w2[oc_out * 256 + k];
    }
}

// =====================================================================
// Fallback path (small ws): separate ROI-align + head reading roi_in
// =====================================================================
__global__ __launch_bounds__(256)
void kRoi(const void* __restrict__ feat, const int* __restrict__ flag,
          const float* __restrict__ boxes, const int* __restrict__ clsArr,
          const float* __restrict__ par, float* __restrict__ roi_in) {
    const int n = blockIdx.x, tid = threadIdx.x;
    const int bf = *flag;
    __shared__ int   x0s[14], x1s[14], y0s[14], y1s[14], vxs[14], vys[14];
    __shared__ float lxs[14], lys[14], cxs[7], cys[7];

    const float bx1 = boxes[n * 5 + 1], by1 = boxes[n * 5 + 2];
    const float bx2 = boxes[n * 5 + 3], by2 = boxes[n * 5 + 4];
    const int b = (int)boxes[n * 5 + 0];

    ROI_META
    __syncthreads();

    for (int t = tid; t < CIN * 49; t += 256) {
        int c = t / 49, p = t % 49, oy = p / 7, ox = p % 7;
        long fb = ((long)b * CIN + c) * HW;
        float acc = 0.f;
#pragma unroll
        for (int dy = 0; dy < 2; ++dy) {
            int sy = oy * 2 + dy;
            float ly = lys[sy]; int yA = y0s[sy], yB = y1s[sy], vy = vys[sy];
#pragma unroll
            for (int dx = 0; dx < 2; ++dx) {
                int sx = ox * 2 + dx;
                float lx = lxs[sx]; int xA = x0s[sx], xB = x1s[sx];
                float v = (1.f - ly) * (1.f - lx) * gload(feat, fb + yA * FW + xA, bf)
                        + (1.f - ly) * lx         * gload(feat, fb + yA * FW + xB, bf)
                        + ly * (1.f - lx)         * gload(feat, fb + yB * FW + xA, bf)
                        + ly * lx                 * gload(feat, fb + yB * FW + xB, bf);
                if (!(vy && vxs[sx])) v = 0.f;
                acc += v;
            }
        }
        roi_in[((long)n * CROI + c) * 49 + p] = acc * 0.25f;
    }
    int cls = clsArr[n];
    for (int t = tid; t < 5 * 49; t += 256) {
        int ch = t / 49, p = t % 49, i = p / 7, j = p % 7;
        float v;
        if (ch == 0)      v = cxs[j];
        else if (ch == 1) v = cys[i];
        else              v = (cls == ch - 2) ? 1.f : 0.f;
        roi_in[((long)n * CROI + 64 + ch) * 49 + p] = v;
    }
}

__global__ __launch_bounds__(256, 4)
void kHeadM(const float* __restrict__ roi_in, const u16* __restrict__ whb,
            const float* __restrict__ par, float* __restrict__ head_out) {
    const int h = blockIdx.x, n = blockIdx.y, tid = threadIdx.x;
    const int wave = tid >> 6, lane = tid & 63;
    const int q = lane >> 4, n15 = lane & 15;
    const int ocArr[4] = {2, 2, 4, 24};
    const int offArr[4] = {0, 2, 4, 8};
    __shared__ __align__(16) u16 r_lds[9][9][104];
    __shared__ float means[256];

    for (int i = tid; i < 9 * 9 * 104 / 8; i += 256)
        ((uint4*)r_lds)[i] = (uint4){0, 0, 0, 0};
    __syncthreads();
    const float* rp = roi_in + (long)n * CROI * 49;
    for (int i = tid; i < CROI * 49; i += 256) {
        int c = i / 49, p = i % 49;
        r_lds[p / 7 + 1][p % 7 + 1][c] = f2b(rp[i]);
    }
    __syncthreads();

    int oyA[4], oxA[4];
#pragma unroll
    for (int i = 0; i < 4; ++i) {
        int pos = i * 16 + n15; if (pos > 48) pos = 48;
        oyA[i] = pos / 7; oxA[i] = pos % 7;
    }

    f32x4 acc[4][4];
#pragma unroll
    for (int i = 0; i < 4; ++i)
#pragma unroll
        for (int t = 0; t < 4; ++t) acc[i][t] = (f32x4){0.f, 0.f, 0.f, 0.f};

#pragma unroll 1
    for (int tap = 0; tap < 9; ++tap) {
        const int ky = tap / 3, kx = tap % 3;
        const u16* wt = whb + ((long)h * 9 + tap) * 24576;
#pragma unroll
        for (int cs = 0; cs < 3; ++cs) {
            short8 afr[4], bfr[4];
#pragma unroll
            for (int i = 0; i < 4; ++i)
                afr[i] = *(const short8*)&r_lds[oyA[i] + ky][oxA[i] + kx][cs * 32 + q * 8];
#pragma unroll
            for (int t = 0; t < 4; ++t)
                bfr[t] = *(const short8*)(wt + ((cs << 8) + wave * 64 + t * 16 + n15) * 32 + q * 8);
#pragma unroll
            for (int i = 0; i < 4; ++i)
#pragma unroll
                for (int t = 0; t < 4; ++t)
                    acc[i][t] = __builtin_amdgcn_mfma_f32_16x16x32_bf16(
                        afr[i], bfr[t], acc[i][t], 0, 0, 0);
        }
    }

    const float* hb = par + PB_HD0 + h * 7456;
#pragma unroll
    for (int t = 0; t < 4; ++t) {
        int oc = wave * 64 + t * 16 + n15;
        float b1 = hb[oc], g = hb[256 + oc], be = hb[512 + oc];
        float m = hb[768 + oc], v = hb[1024 + oc];
        float scale = g / sqrtf(v + 1e-5f);
        float s = 0.f;
#pragma unroll
        for (int i = 0; i < 4; ++i)
#pragma unroll
            for (int r = 0; r < 4; ++r) {
                int pos = i * 16 + q * 4 + r;
                if (pos < 49)
                    s += fmaxf((acc[i][t][r] + b1 - m) * scale + be, 0.f);
            }
        s += __shfl_xor(s, 16);
        s += __shfl_xor(s, 32);
        if (q == 0) means[oc] = s / 49.f;
    }
    __syncthreads();

    int oc_out = ocArr[h];
    const float* w2 = hb + 1280;
    for (int k = wave; k < oc_out; k += 4) {
        float s = 0.f;
        for (int c = lane; c < 256; c += 64) s += means[c] * w2[k * 256 + c];
#pragma unroll
        for (int off = 32; off > 0; off >>= 1) s += __shfl_down(s, off);
        if (lane == 0)
            head_out[(long)n * 32 + offArr[h] + k] = s + w2[oc_out * 256 + k];
    }
}

// =====================================================================
// Final scalar math + small outputs
// =====================================================================
__global__ void kFinal(const float* __restrict__ head_out, const float* __restrict__ boxes,
                       const int* __restrict__ clsArr, const float* __restrict__ par,
                       void* __restrict__ out, const int* __restrict__ flag) {
    int n = blockIdx.x * 256 + threadIdx.x;
    if (n >= NROI) return;
    const int bf = *flag;
    const float* ho = head_out + (long)n * 32;
    float dep0 = ho[0], dep1 = ho[1];
    int b = (int)boxes[n * 5 + 0];
    int cls = clsArr[n];

    for (int j = 0; j < 24; ++j) gstore(out, O_HEAD + n * 24 + j, ho[8 + j], bf);
    gstore(out, O_OFF3 + n * 2 + 0, ho[2], bf);
    gstore(out, O_OFF3 + n * 2 + 1, ho[3], bf);
    gstore(out, O_S3D + n * 3 + 0, ho[4], bf);
    gstore(out, O_S3D + n * 3 + 1, ho[5], bf);
    gstore(out, O_S3D + n * 3 + 2, ho[6], bf);
    gstore(out, O_H3D + n, ho[7], bf);

    float cry0 = par[PB_CRN + b * 4 + 1], cry1 = par[PB_CRN + b * 4 + 3];
    float sy = cry1 - cry0;
    float bi2 = boxes[n * 5 + 2] / (float)FH * sy + cry0;
    float bi4 = boxes[n * 5 + 4] / (float)FH * sy + cry0;
    float box_h = fmaxf(bi4 - bi2, 1.f);
    float f_u = par[PB_CAL + b * 12 + 0];
    float size3d0 = par[PB_MSZ + cls * 3 + 0] + ho[4];
    float depth_geo = size3d0 / box_h * f_u;
    float sig = 1.f / (1.f + expf(-dep0));
    float d0 = 1.f / (sig + 1e-6f) - 1.f + depth_geo;
    float dgls = ho[7] + 2.f * (logf(f_u) - logf(box_h));
    float mx = fmaxf(dep1, dgls);
    float lse = mx + logf(expf(dep1 - mx) + expf(dgls - mx));
    gstore(out, O_DEP + n * 2 + 0, d0, bf);
    gstore(out, O_DEP + n * 2 + 1, lse, bf);
}

// =====================================================================
extern "C" void kernel_launch(void* const* d_in, const int* in_sizes, int n_in,
                              void* d_out, int out_size, void* d_ws, size_t ws_size,
                              hipStream_t stream) {
    (void)in_sizes; (void)n_in; (void)out_size;
    float* ws = (float*)d_ws;
    float* par = ws + WS_PAR;
    int* flag = (int*)(ws + WS_FLAG);
    u16* wb16 = (u16*)(ws + WS_WB16);
    u16* whb  = (u16*)(ws + WS_W1H);
    u16* featT = (u16*)(ws + WS_FEATT);
    const void* feat = d_in[0];
    const bool bigws = ws_size >= (size_t)WS_END * 4;

    WPtrs WP;
    WP.bw[0] = d_in[4]; WP.bw[1] = d_in[8]; WP.bw[2] = d_in[12];
    WP.hw[0] = d_in[16]; WP.hw[1] = d_in[24]; WP.hw[2] = d_in[32]; WP.hw[3] = d_in[40];

    Segs SG; int si = 0;
    auto add = [&](const void* s, int n, int dst) {
        SG.s[si].src = s; SG.s[si].n = n; SG.s[si].dst = dst; ++si;
    };
    add(d_in[1], 96, PB_CAL); add(d_in[2], 32, PB_CRN); add(d_in[3], 9, PB_MSZ);
    const int ocb[3] = {3, 2, 2};
    for (int b = 0; b < 3; ++b) {
        int base = PB_BR0 + b * 1040;
        int i0 = 4 + 4 * b;
        add(d_in[i0 + 1], 256, base);
        add(d_in[i0 + 2], ocb[b] * 256, base + 256);
        add(d_in[i0 + 3], ocb[b], base + 256 + ocb[b] * 256);
    }
    const int och[4] = {2, 2, 4, 24};
    for (int h = 0; h < 4; ++h) {
        int base = PB_HD0 + h * 7456;
        int i0 = 16 + 8 * h;
        add(d_in[i0 + 1], 256, base);
        add(d_in[i0 + 2], 256, base + 256);
        add(d_in[i0 + 3], 256, base + 512);
        add(d_in[i0 + 4], 256, base + 768);
        add(d_in[i0 + 5], 256, base + 1024);
        add(d_in[i0 + 6], och[h] * 256, base + 1280);
        add(d_in[i0 + 7], och[h], base + 1280 + och[h] * 256);
    }
    SG.cnt = si;

    kPrepWP<<<5760 + 40, 256, 0, stream>>>(WP, SG, feat, flag,
                                           ws + WS_W1T, wb16, whb, par);

    // mega dispatch: strip first (z==0) so it overlaps conv (z=1..8);
    // conv role also emits featT (transpose role removed)
    kBranch3M<<<dim3(5, 48, 9), 512, 0, stream>>>(
        feat, flag, wb16, par + PB_BR0, ws + WS_W1T, d_out, ws, bigws ? 1 : 0);

    kNmsTopA<<<dim3(24, NCHUNK), 256, 0, stream>>>(ws + WS_HEAT, ws + WS_NH);
    kTopBC<<<8, 192, 0, stream>>>(ws + WS_NH, ws + WS_OFF2, ws + WS_SIZ2,
                                  ws + WS_BOX, (int*)(ws + WS_CLS));
    if (bigws) {
        kHeadM2<<<dim3(4, NROI), 256, 0, stream>>>(featT, ws + WS_BOX,
                                                   (int*)(ws + WS_CLS), whb, par,
                                                   ws + WS_HOUT);
    } else {
        kRoi<<<400, 256, 0, stream>>>(feat, flag, ws + WS_BOX, (int*)(ws + WS_CLS),
                                      par, ws + WS_ROI);
        kHeadM<<<dim3(4, NROI), 256, 0, stream>>>(ws + WS_ROI, whb, par, ws + WS_HOUT);
    }
    kFinal<<<2, 256, 0, stream>>>(ws + WS_HOUT, ws + WS_BOX, (int*)(ws + WS_CLS),
                                  par, d_out, flag);
}

// Round 6
// 754.485 us; speedup vs baseline: 1.1150x; 1.0007x over previous
//
#include <hip/hip_runtime.h>
#include <math.h>

typedef unsigned short u16;
typedef unsigned int   u32;
typedef unsigned long long u64;
typedef __attribute__((ext_vector_type(8))) short short8;   // 8 bf16 (4 VGPR)
typedef __attribute__((ext_vector_type(4))) float f32x4;    // MFMA acc

// ---------- dtype helpers ----------
__device__ __forceinline__ float b2f(u16 v) { return __uint_as_float(((u32)v) << 16); }
__device__ __forceinline__ u16 f2b(float f) {
    u32 u = __float_as_uint(f);
    u32 r = (u + 0x7FFFu + ((u >> 16) & 1u)) >> 16;   // RNE
    return (u16)r;
}
__device__ __forceinline__ float gload(const void* p, long i, int bf) {
    return bf ? b2f(((const u16*)p)[i]) : ((const float*)p)[i];
}
__device__ __forceinline__ void gstore(void* p, long i, float v, int bf) {
    if (bf) ((u16*)p)[i] = f2b(v);
    else    ((float*)p)[i] = v;
}

// top-k key: smallest key = (largest value, then smallest index)
__device__ __forceinline__ u64 packKey(float v, int idx) {
    u32 u = __float_as_uint(v);
    u32 m = (u & 0x80000000u) ? ~u : (u | 0x80000000u);   // monotone float->uint
    return ((u64)(~m) << 32) | (u32)idx;
}

// per-block dtype-flag recompute (512 u16 probe of feat)
__device__ int blockFlag(const void* feat) {
    __shared__ int fcnt;
    if (threadIdx.x == 0) fcnt = 0;
    __syncthreads();
    int sane = 0;
    for (int i = threadIdx.x; i < 512; i += blockDim.x) {
        u16 v = ((const u16*)feat)[i];
        float f = b2f(v);
        u32 e = (v >> 7) & 0xFF;
        float a = fabsf(f);
        sane += (e != 0xFF) && (f == 0.f || (a >= 1e-8f && a <= 1e4f));
    }
    atomicAdd(&fcnt, sane);
    __syncthreads();
    return fcnt >= 480;
}

// ---------- problem constants ----------
#define BATCH 8
#define CIN   64
#define FH    96
#define FW    320
#define KDET  50
#define NROI  400
#define CROI  69
#define HW    (FH*FW)
#define CHUNK 1920
#define NCHUNK 16

// ---------- workspace layout (float offsets) ----------
#define WS_HEAT 0L
#define WS_OFF2 737280L
#define WS_SIZ2 1228800L
#define WS_NH   1720320L
#define WS_CLS  2460000L
#define WS_BOX  2460400L
#define WS_ROI  2462400L
#define WS_HOUT 3814800L
#define WS_W1T  3827600L     // 147456 f32: hm conv1 [k=576][c=256] (exact strip)
#define WS_WB16 3975056L     // u16: 3 branches * [9][2][256][32] bf16 (lane-coalesced)
#define WS_W1H  4269968L     // u16: 4 heads * [9][3][256][32] bf16
#define WS_PAR  4905872L     // packed f32 params
#define WS_FLAG 4938960L     // int dtype flag
#define WS_FEATT 4938964L    // u16: [8][96][320][64] bf16 transposed features
#define WS_END  (WS_FEATT + 7864320L)

// param block sub-offsets
#define PB_CAL 0
#define PB_CRN 96
#define PB_MSZ 128
#define PB_BR0 144          // stride 1040: b1@0, w2@256 ([k][n]), b2@256+OC*256
#define PB_HD0 3264         // stride 7456

// ---------- output layout (element offsets) ----------
#define O_HEAT 0L
#define O_OFF2 737280L
#define O_SIZ2 1228800L
#define O_HEAD 1720320L
#define O_DEP  1729920L
#define O_OFF3 1730720L
#define O_S3D  1731520L
#define O_H3D  1732720L

// =====================================================================
// Fused prep: weights + params + flag
// =====================================================================
struct WPtrs { const void* bw[3]; const void* hw[4]; };
struct Seg { const void* src; int n; int dst; };
struct Segs { Seg s[40]; int cnt; };

__global__ void kPrepWP(WPtrs P, Segs S, const void* __restrict__ feat,
                        int* __restrict__ flag, float* __restrict__ w1t,
                        u16* __restrict__ wb16, u16* __restrict__ whb,
                        float* __restrict__ par) {
    const int bf = blockFlag(feat);
    if (blockIdx.x == 0 && threadIdx.x == 0) *flag = bf;
    if (blockIdx.x < 5760) {
        int idx = blockIdx.x * 256 + threadIdx.x;
        if (idx < 147456) {
            int k = idx >> 8, c = idx & 255;
            w1t[idx] = gload(P.bw[0], (long)c * 576 + k, bf);
        } else if (idx < 589824) {
            int j = idx - 147456;
            int br = j / 147456, rem = j % 147456;
            int tap = rem / 16384;
            int r2 = rem & 16383;
            int s = r2 >> 13;
            int n = (r2 >> 5) & 255;
            int c5 = r2 & 31;
            int ci = s * 32 + c5;
            wb16[j] = f2b(gload(P.bw[br], (long)n * 576 + ci * 9 + tap, bf));
        } else {
            int j = idx - 589824;               // < 884736
            int h = j / 221184, rem = j % 221184;
            int tap = rem / 24576, rem2 = rem % 24576;
            int cs = rem2 / 8192, rem3 = rem2 % 8192;
            int oc = rem3 >> 5, jj = rem3 & 31;
            int ci = cs * 32 + jj;
            u16 val = 0;
            if (ci < CROI) val = f2b(gload(P.hw[h], (long)oc * 621 + ci * 9 + tap, bf));
            whb[j] = val;
        }
    } else {
        int sidx = blockIdx.x - 5760;
        if (sidx < S.cnt) {
            Seg sg = S.s[sidx];
            for (int i = threadIdx.x; i < sg.n; i += 256)
                par[sg.dst + i] = gload(sg.src, i, bf);
        }
    }
}

// =====================================================================
// Mega branch dispatch: grid (5, 48, 10)
//   z==0 : exact f32 strip role (heat rows 0..2)  -- dispatched FIRST
//   z==1 : feature transpose role (early-returns if !doT)
//   z>=2 : MFMA conv role (b=z-2); heat stores skip rows 0..2
//   (roles byte-identical to the 742us baseline; only z-order changed so
//    the long-pole strip/transpose blocks overlap conv instead of tailing)
// =====================================================================
union MLds {
    struct { u16 a[4][68][72]; float red[8][64][3]; } c;
    struct {
        float in[4][3][36];
        union { float w[36 * 256]; float part[32 * 3 * 32]; } u;
    } s;
    u16 t[64][72];
};

__global__ __launch_bounds__(512, 4)
void kBranch3M(const void* __restrict__ feat, const int* __restrict__ flag,
               const u16* __restrict__ wbAll,   // 3 * [9][2][256][32] bf16
               const float* __restrict__ bpAll, // par + PB_BR0, stride 1040
               const float* __restrict__ w1t,   // strip weights f32
               void* __restrict__ outb, float* __restrict__ wsbase, int doT) {
    __shared__ __align__(16) MLds L;

    const long obase[3] = {O_HEAT, O_OFF2, O_SIZ2};
    const long wfs[3]   = {WS_HEAT, WS_OFF2, WS_SIZ2};

    const int bfl = *flag;
    const int tid = threadIdx.x;

    if (blockIdx.z == 1) {
        // ================= TRANSPOSE ROLE: [b][c][h][w]->[b][h][w][c] ==
        if (!doT) return;
        u16* featT = (u16*)(wsbase + WS_FEATT);
        const int x0 = blockIdx.x * 64;
        const int y0 = blockIdx.y * 2;
        for (int sub = 0; sub < 16; ++sub) {       // 8 b x 2 rows
            const int b = sub >> 1, y = y0 + (sub & 1);
            __syncthreads();
            for (int i = tid; i < 64 * 64; i += 512) {
                int c = i >> 6, x = i & 63;        // lanes: consecutive x
                L.t[x][c] = f2b(gload(feat, ((long)(b * CIN + c) * FH + y) * FW + x0 + x, bfl));
            }
            __syncthreads();
            u16* outp = featT + (((long)b * FH + y) * FW + x0) * 64;
            for (int i = tid; i < 64 * 64; i += 512) {
                int x = i >> 6, c = i & 63;        // lanes: consecutive c
                outp[(long)x * 64 + c] = L.t[x][c];
            }
        }
        return;
    }

    if (blockIdx.z == 0) {
        // ================= STRIP ROLE (exact f32, rows 0..2) ==========
        const int sidx = blockIdx.y * 5 + blockIdx.x;   // 0..239
        const int x0 = (sidx % 10) * 32;
        const int srem = sidx / 10;
        const int y = srem % 3;
        const int b = srem / 3;
        const float* bp = bpAll;                        // heat branch params
        const int OC = 3;
        const int xg = tid & 7, cg = tid >> 3;
        const int c0 = (cg & 31) * 8;

        float acc[8][4];
#pragma unroll
        for (int i = 0; i < 8; ++i)
#pragma unroll
            for (int j = 0; j < 4; ++j) acc[i][j] = 0.f;

        for (int chunk = 0; chunk < 16; ++chunk) {
            const int ci0 = chunk * 4;
            __syncthreads();
            for (int i = tid; i < 4 * 3 * 36; i += 512) {
                int xx = i % 36, t2 = i / 36;
                int r = t2 % 3, ci = t2 / 3;
                int gx = x0 - 1 + xx, gy = y - 1 + r;
                float v = 0.f;
                if (gx >= 0 && gx < FW && gy >= 0 && gy < FH)
                    v = gload(feat, ((long)(b * CIN + ci0 + ci) * FH + gy) * FW + gx, bfl);
                L.s.in[ci][r][xx] = v;
            }
            {
                const float4* src = (const float4*)(w1t + (long)ci0 * 9 * 256);
                float4* dst = (float4*)L.s.u.w;
                for (int i = tid; i < 36 * 256 / 4; i += 512) dst[i] = src[i];
            }
            __syncthreads();
            if (tid < 256) {
#pragma unroll
                for (int ci = 0; ci < 4; ++ci) {
#pragma unroll
                    for (int ky = 0; ky < 3; ++ky) {
                        const float* rowp = &L.s.in[ci][ky][xg * 4];
                        float inv[6];
                        *(float4*)&inv[0] = *(const float4*)&rowp[0];
                        *(float2*)&inv[4] = *(const float2*)&rowp[4];
#pragma unroll
                        for (int kx = 0; kx < 3; ++kx) {
                            const float* wp = &L.s.u.w[(ci * 9 + ky * 3 + kx) * 256 + c0];
                            float wv[8];
                            *(float4*)&wv[0] = *(const float4*)&wp[0];
                            *(float4*)&wv[4] = *(const float4*)&wp[4];
#pragma unroll
                            for (int cc = 0; cc < 8; ++cc)
#pragma unroll
                                for (int xx = 0; xx < 4; ++xx)
                                    acc[cc][xx] = fmaf(wv[cc], inv[xx + kx], acc[cc][xx]);
                        }
                    }
                }
            }
        }

        if (tid < 256) {
#pragma unroll
            for (int cc = 0; cc < 8; ++cc) {
                float b1v = bp[c0 + cc];
#pragma unroll
                for (int xx = 0; xx < 4; ++xx)
                    acc[cc][xx] = fmaxf(acc[cc][xx] + b1v, 0.f);
            }
        }
        __syncthreads();
        if (tid < 256) {
#pragma unroll
            for (int k = 0; k < OC; ++k) {
                float p[4];
#pragma unroll
                for (int xx = 0; xx < 4; ++xx) p[xx] = 0.f;
#pragma unroll
                for (int cc = 0; cc < 8; ++cc) {
                    float wv = bp[256 + k * 256 + c0 + cc];
#pragma unroll
                    for (int xx = 0; xx < 4; ++xx) p[xx] = fmaf(acc[cc][xx], wv, p[xx]);
                }
#pragma unroll
                for (int xx = 0; xx < 4; ++xx)
                    L.s.u.part[((cg & 31) * OC + k) * 32 + xg * 4 + xx] = p[xx];
            }
        }
        __syncthreads();
        float* outf = wsbase + WS_HEAT;
        for (int t = tid; t < OC * 32; t += 512) {
            int k = t >> 5, xx = t & 31;
            float s = bp[256 + OC * 256 + k];
#pragma unroll 8
            for (int g = 0; g < 32; ++g) s += L.s.u.part[(g * OC + k) * 32 + xx];
            long o = (((long)b * OC + k) * FH + y) * FW + x0 + xx;
            gstore(outb, O_HEAT + o, s, bfl);
            outf[o] = s;
        }
        return;
    }

    // ==================== CONV ROLE (MFMA) ============================
    const int wave = tid >> 6, lane = tid & 63;
    const int q = lane >> 4, n15 = lane & 15;
    const int mg = wave >> 2, ng = wave & 3;
    const int x0 = blockIdx.x * 64, y0 = blockIdx.y * 2;
    const int b = blockIdx.z - 2;

    // staging with all 512 threads (each of 8 waves covers half a row-pair)
    {
        const int ci = tid & 63, rr = (tid >> 6) & 3, hf = tid >> 8;
        const int gy = y0 - 1 + rr;
        if (gy < 0 || gy >= FH) {
            for (int xi = hf * 33; xi < hf * 33 + 33; ++xi) L.c.a[rr][xi][ci] = 0;
        } else if (bfl) {
            const u16* rp = (const u16*)feat + ((long)((b << 6) | ci) * FH + gy) * FW;
            for (int j = hf * 5; j < hf * 5 + 5; ++j) {
                int xs0 = x0 - 8 + j * 8;
                u16 tmp[8];
                if (xs0 >= 0 && xs0 <= FW - 8)
                    *(uint4*)tmp = *(const uint4*)(rp + xs0);
                else
                    for (int e = 0; e < 8; ++e) {
                        int gx = xs0 + e;
                        tmp[e] = (gx >= 0 && gx < FW) ? rp[gx] : (u16)0;
                    }
                for (int e = 0; e < 8; ++e) {
                    int xi = xs0 + e - x0 + 1;
                    if (xi >= 0 && xi < 66) L.c.a[rr][xi][ci] = tmp[e];
                }
            }
        } else {
            const float* rp = (const float*)feat + ((long)((b << 6) | ci) * FH + gy) * FW;
            for (int j = hf * 9; j < hf * 9 + 9; ++j) {
                int xs0 = x0 - 4 + j * 4;
                float tmp[4];
                if (xs0 >= 0 && xs0 <= FW - 4)
                    *(float4*)tmp = *(const float4*)(rp + xs0);
                else
                    for (int e = 0; e < 4; ++e) {
                        int gx = xs0 + e;
                        tmp[e] = (gx >= 0 && gx < FW) ? rp[gx] : 0.f;
                    }
                for (int e = 0; e < 4; ++e) {
                    int xi = xs0 + e - x0 + 1;
                    if (xi >= 0 && xi < 66) L.c.a[rr][xi][ci] = f2b(tmp[e]);
                }
            }
        }
    }
    __syncthreads();   // a_lds visible; read-only from here on

#pragma unroll 1
    for (int br = 0; br < 3; ++br) {
        const int oc = (br == 0) ? 3 : 2;
        const u16* wpt = wbAll + br * 147456;
        const float* bp = bpAll + br * 1040;

        f32x4 acc[4][4];
#pragma unroll
        for (int i = 0; i < 4; ++i)
#pragma unroll
            for (int t = 0; t < 4; ++t) acc[i][t] = (f32x4){0.f, 0.f, 0.f, 0.f};

#pragma unroll 1
        for (int tap = 0; tap < 9; ++tap) {
            const int ky = tap / 3, kx = tap % 3;
#pragma unroll
            for (int s = 0; s < 2; ++s) {
                const u16* wks = wpt + (tap * 2 + s) * 8192;
                short8 bfr[4];
#pragma unroll
                for (int t = 0; t < 4; ++t)
                    bfr[t] = *(const short8*)(wks + (ng * 64 + t * 16 + n15) * 32 + q * 8);
                short8 afr[4];
#pragma unroll
                for (int i = 0; i < 4; ++i)
                    afr[i] = *(const short8*)&L.c.a[mg + ky][i * 16 + n15 + kx][s * 32 + q * 8];
#pragma unroll
                for (int i = 0; i < 4; ++i)
#pragma unroll
                    for (int t = 0; t < 4; ++t)
                        acc[i][t] = __builtin_amdgcn_mfma_f32_16x16x32_bf16(
                            afr[i], bfr[t], acc[i][t], 0, 0, 0);
            }
        }

        float b1v[4], w2v[3][4];
#pragma unroll
        for (int t = 0; t < 4; ++t) {
            int n = ng * 64 + t * 16 + n15;
            b1v[t] = bp[n];
#pragma unroll
            for (int k = 0; k < 3; ++k) w2v[k][t] = bp[256 + k * 256 + n];
        }
        __syncthreads();
#pragma unroll
        for (int i = 0; i < 4; ++i) {
#pragma unroll
            for (int r = 0; r < 4; ++r) {
                float pk[3];
#pragma unroll
                for (int k = 0; k < 3; ++k) pk[k] = 0.f;
#pragma unroll
                for (int t = 0; t < 4; ++t) {
                    float h = fmaxf(acc[i][t][r] + b1v[t], 0.f);
#pragma unroll
                    for (int k = 0; k < 3; ++k) pk[k] = fmaf(h, w2v[k][t], pk[k]);
                }
#pragma unroll
                for (int k = 0; k < 3; ++k) {
                    pk[k] += __shfl_xor(pk[k], 1);
                    pk[k] += __shfl_xor(pk[k], 2);
                    pk[k] += __shfl_xor(pk[k], 4);
                    pk[k] += __shfl_xor(pk[k], 8);
                }
                if (n15 == 0) {
                    int ml = i * 16 + q * 4 + r;
#pragma unroll
                    for (int k = 0; k < 3; ++k) L.c.red[wave][ml][k] = pk[k];
                }
            }
        }
        __syncthreads();
        float* outf = wsbase + wfs[br];
        for (int t2 = tid; t2 < oc * 128; t2 += 512) {
            int k = t2 >> 7, m = t2 & 127;
            int row = m >> 6, x = m & 63;
            int mg2 = m >> 6, ml = m & 63;
            float s = bp[256 + oc * 256 + k];
#pragma unroll
            for (int w = 0; w < 4; ++w) s += L.c.red[mg2 * 4 + w][ml][k];
            int grow = y0 + row;
            if (br == 0 && grow < 3) continue;    // strip role owns heat rows 0..2
            long o = (((long)b * oc + k) * FH + grow) * FW + x0 + x;
            gstore(outb, obase[br] + o, s, bfl);
            outf[o] = s;
        }
    }
}

// =====================================================================
// Fused NMS + top-k stage A (4-wave hierarchical extraction)
// =====================================================================
__global__ __launch_bounds__(256)
void kNmsTopA(const float* __restrict__ heat, float* __restrict__ nh) {
    __shared__ float hrow[8][320];
    __shared__ u64 keys[CHUNK];
    __shared__ u64 sub[4][KDET];
    const int bc = blockIdx.x, ch = blockIdx.y;
    const int tid = threadIdx.x;
    const int wave = tid >> 6, lane = tid & 63;
    const int r0 = ch * 6;
    const float* hp = heat + (long)bc * HW;

    for (int i = tid; i < 8 * 320; i += 256) {
        int rr = i / 320, x = i % 320;
        int gy = r0 - 1 + rr;
        hrow[rr][x] = (gy >= 0 && gy < FH) ? hp[(long)gy * FW + x] : -INFINITY;
    }
    __syncthreads();
    for (int i = tid; i < CHUNK; i += 256) {
        int ry = i / 320, x = i % 320;
        float v = hrow[ry + 1][x];
        float m = v;
        int xm = max(x - 1, 0), xp = min(x + 1, FW - 1);
#pragma unroll
        for (int dy = 0; dy < 3; ++dy) {
            m = fmaxf(m, hrow[ry + dy][xm]);
            m = fmaxf(m, hrow[ry + dy][x]);
            m = fmaxf(m, hrow[ry + dy][xp]);
        }
        float nv = (v == m) ? v : 0.f;
        keys[i] = packKey(nv, ch * CHUNK + i);
    }
    __syncthreads();
    // each wave: top-50 of its 480-element sub-chunk
    {
        u64* kw = keys + wave * 480;
        for (int it = 0; it < KDET; ++it) {
            u64 bk = ~0ULL; int bp = 0;
            for (int i = lane; i < 480; i += 64) {
                u64 k = kw[i];
                if (k < bk) { bk = k; bp = i; }
            }
#pragma unroll
            for (int s = 32; s > 0; s >>= 1) {
                u64 k2 = __shfl_down(bk, s);
                int p2 = __shfl_down(bp, s);
                if (k2 < bk) { bk = k2; bp = p2; }
            }
            bk = __shfl(bk, 0);
            bp = __shfl(bp, 0);
            if (lane == 0) {
                sub[wave][it] = bk;
                kw[bp] = ~0ULL;
            }
        }
    }
    __syncthreads();
    // wave 0: merge 4x50 -> chunk top-50
    if (wave == 0) {
        u64* outp = (u64*)(nh + (long)bc * HW + (long)ch * CHUNK);
        u64* sp = &sub[0][0];
        for (int it = 0; it < KDET; ++it) {
            u64 bk = ~0ULL; int bp = 0;
            for (int i = lane; i < 4 * KDET; i += 64) {
                u64 k = sp[i];
                if (k < bk) { bk = k; bp = i; }
            }
#pragma unroll
            for (int s = 32; s > 0; s >>= 1) {
                u64 k2 = __shfl_down(bk, s);
                int p2 = __shfl_down(bp, s);
                if (k2 < bk) { bk = k2; bp = p2; }
            }
            bk = __shfl(bk, 0);
            bp = __shfl(bp, 0);
            if (lane == 0) {
                outp[it] = bk;
                sp[bp] = ~0ULL;
            }
        }
    }
}

// =====================================================================
// Fused top-k stage B + stage 2 + boxes
// =====================================================================
__global__ __launch_bounds__(192)
void kTopBC(const float* __restrict__ nh, const float* __restrict__ off2,
            const float* __restrict__ siz2, float* __restrict__ boxes,
            int* __restrict__ clsArr) {
    __shared__ u64 keys[3][NCHUNK * KDET];
    __shared__ float sc[150];
    __shared__ int   si[150];
    const int b = blockIdx.x, tid = threadIdx.x;
    const int wave = tid >> 6, lane = tid & 63;
    const int bc = b * 3 + wave;

    for (int ch = 0; ch < NCHUNK; ++ch) {
        const u64* src = (const u64*)(nh + (long)bc * HW + (long)ch * CHUNK);
        if (lane < KDET) keys[wave][ch * KDET + lane] = src[lane];
    }
    __syncthreads();
    for (int it = 0; it < KDET; ++it) {
        u64 bk = ~0ULL; int bp = 0;
        for (int i = lane; i < NCHUNK * KDET; i += 64) {
            u64 k = keys[wave][i];
            if (k < bk) { bk = k; bp = i; }
        }
#pragma unroll
        for (int s = 32; s > 0; s >>= 1) {
            u64 k2 = __shfl_down(bk, s);
            int p2 = __shfl_down(bp, s);
            if (k2 < bk) { bk = k2; bp = p2; }
        }
        bk = __shfl(bk, 0);
        bp = __shfl(bp, 0);
        if (lane == 0) {
            u32 hm = ~(u32)(bk >> 32);
            u32 u = (hm & 0x80000000u) ? (hm & 0x7fffffffu) : ~hm;
            sc[wave * KDET + it] = __uint_as_float(u);
            si[wave * KDET + it] = (int)(bk & 0xFFFFFFFFu);
            keys[wave][bp] = ~0ULL;
        }
    }
    __syncthreads();
    if (wave == 0) {
        const int t = lane;
        for (int r = 0; r < KDET; ++r) {
            float bv = -INFINITY; int bp = 0x7fffffff;
            for (int i = t; i < 150; i += 64) {
                float v = sc[i];
                if (v > bv) { bv = v; bp = i; }
            }
#pragma unroll
            for (int s = 32; s > 0; s >>= 1) {
                float v2 = __shfl_down(bv, s);
                int   p2 = __shfl_down(bp, s);
                if (v2 > bv || (v2 == bv && p2 < bp)) { bv = v2; bp = p2; }
            }
            bp = __shfl(bp, 0);
            if (t == 0) {
                int cls = bp / KDET;
                int ind = si[bp];
                int n = b * KDET + r;
                clsArr[n] = cls;
                int x = ind % FW, yy = ind / FW;
                float cx = (float)x  + off2[(((long)b * 2 + 0) * FH + yy) * FW + x];
                float cy = (float)yy + off2[(((long)b * 2 + 1) * FH + yy) * FW + x];
                float w  = siz2[(((long)b * 2 + 0) * FH + yy) * FW + x];
                float h  = siz2[(((long)b * 2 + 1) * FH + yy) * FW + x];
                boxes[n * 5 + 0] = (float)b;
                boxes[n * 5 + 1] = cx - w * 0.5f;
                boxes[n * 5 + 2] = cy - h * 0.5f;
                boxes[n * 5 + 3] = cx + w * 0.5f;
                boxes[n * 5 + 4] = cy + h * 0.5f;
                sc[bp] = -INFINITY;
            }
        }
    }
}

// =====================================================================
// ROI metadata helper
// =====================================================================
#define ROI_META \
    if (tid < 14) { \
        float roi_w = fmaxf(bx2 - bx1, 1.f); \
        float X = bx1 + (roi_w / 7.f) * ((tid + 0.5f) * 0.5f); \
        vxs[tid] = (X > -1.f) && (X < (float)FW); \
        float Xc = fminf(fmaxf(X, 0.f), (float)(FW - 1)); \
        int xi = (int)floorf(Xc); \
        x0s[tid] = xi; x1s[tid] = min(xi + 1, FW - 1); lxs[tid] = Xc - (float)xi; \
    } else if (tid >= 16 && tid < 30) { \
        int i = tid - 16; \
        float roi_h = fmaxf(by2 - by1, 1.f); \
        float Y = by1 + (roi_h / 7.f) * ((i + 0.5f) * 0.5f); \
        vys[i] = (Y > -1.f) && (Y < (float)FH); \
        float Yc = fminf(fmaxf(Y, 0.f), (float)(FH - 1)); \
        int yi = (int)floorf(Yc); \
        y0s[i] = yi; y1s[i] = min(yi + 1, FH - 1); lys[i] = Yc - (float)yi; \
    } else if (tid >= 32 && tid < 46) { \
        int j = tid - 32; \
        const float* cal = par + PB_CAL + b * 12; \
        float f_u = cal[0], c_u = cal[2], t03 = cal[3]; \
        float f_v = cal[5], c_v = cal[6], t13 = cal[7]; \
        float bxc = t03 / (-f_u), byc = t13 / (-f_v); \
        const float* cr = par + PB_CRN + b * 4; \
        float crx0 = cr[0], cry0 = cr[1], crx1 = cr[2], cry1 = cr[3]; \
        float sx = crx1 - crx0, sy = cry1 - cry0; \
        float u1 = bx1 / (float)FW * sx + crx0, v1 = by1 / (float)FH * sy + cry0; \
        float u2 = bx2 / (float)FW * sx + crx0, v2 = by2 / (float)FH * sy + cry0; \
        float p1x = (u1 - c_u) / f_u + bxc, p1y = (v1 - c_v) / f_v + byc; \
        float p2x = (u2 - c_u) / f_u + bxc, p2y = (v2 - c_v) / f_v + byc; \
        if (j < 7) cxs[j] = p1x + ((float)j / 6.f) * (p2x - p1x); \
        else       cys[j - 7] = p1y + ((float)(j - 7) / 6.f) * (p2y - p1y); \
    }

// =====================================================================
// Fused ROI-align + MFMA head (bigws path): stages r_lds directly from
// transposed features (coalesced corners), then conv+BN+mean+1x1.
// =====================================================================
__global__ __launch_bounds__(256, 4)
void kHeadM2(const u16* __restrict__ featT, const float* __restrict__ boxes,
             const int* __restrict__ clsArr, const u16* __restrict__ whb,
             const float* __restrict__ par, float* __restrict__ head_out) {
    const int h = blockIdx.x, n = blockIdx.y, tid = threadIdx.x;
    const int wave = tid >> 6, lane = tid & 63;
    const int q = lane >> 4, n15 = lane & 15;
    const int ocArr[4] = {2, 2, 4, 24};
    const int offArr[4] = {0, 2, 4, 8};
    __shared__ __align__(16) u16 r_lds[9][9][104];
    __shared__ float means[256];
    __shared__ int   x0s[14], x1s[14], y0s[14], y1s[14], vxs[14], vys[14];
    __shared__ float lxs[14], lys[14], cxs[7], cys[7];

    const float bx1 = boxes[n * 5 + 1], by1 = boxes[n * 5 + 2];
    const float bx2 = boxes[n * 5 + 3], by2 = boxes[n * 5 + 4];
    const int b = (int)boxes[n * 5 + 0];
    ROI_META

    for (int i = tid; i < 9 * 9 * 104 / 8; i += 256)
        ((uint4*)r_lds)[i] = (uint4){0, 0, 0, 0};
    __syncthreads();

    const u16* fb = featT + (long)b * FH * FW * 64;
    for (int t = tid; t < CIN * 49; t += 256) {
        int c = t & 63, p = t >> 6;        // lanes: consecutive c (coalesced)
        int oy = p / 7, ox = p % 7;
        float acc = 0.f;
#pragma unroll
        for (int dy = 0; dy < 2; ++dy) {
            int sy = oy * 2 + dy;
            float ly = lys[sy]; int yA = y0s[sy], yB = y1s[sy], vy = vys[sy];
#pragma unroll
            for (int dx = 0; dx < 2; ++dx) {
                int sx = ox * 2 + dx;
                float lx = lxs[sx]; int xA = x0s[sx], xB = x1s[sx];
                float v = (1.f - ly) * (1.f - lx) * b2f(fb[((long)yA * FW + xA) * 64 + c])
                        + (1.f - ly) * lx         * b2f(fb[((long)yA * FW + xB) * 64 + c])
                        + ly * (1.f - lx)         * b2f(fb[((long)yB * FW + xA) * 64 + c])
                        + ly * lx                 * b2f(fb[((long)yB * FW + xB) * 64 + c]);
                if (!(vy && vxs[sx])) v = 0.f;
                acc += v;
            }
        }
        r_lds[oy + 1][ox + 1][c] = f2b(acc * 0.25f);
    }
    {
        int cls = clsArr[n];
        for (int t = tid; t < 5 * 49; t += 256) {
            int ch = t / 49, p = t % 49, i = p / 7, j = p % 7;
            float v;
            if (ch == 0)      v = cxs[j];
            else if (ch == 1) v = cys[i];
            else              v = (cls == ch - 2) ? 1.f : 0.f;
            r_lds[i + 1][j + 1][64 + ch] = f2b(v);
        }
    }
    __syncthreads();

    int oyA[4], oxA[4];
#pragma unroll
    for (int i = 0; i < 4; ++i) {
        int pos = i * 16 + n15; if (pos > 48) pos = 48;
        oyA[i] = pos / 7; oxA[i] = pos % 7;
    }

    f32x4 acc[4][4];
#pragma unroll
    for (int i = 0; i < 4; ++i)
#pragma unroll
        for (int t = 0; t < 4; ++t) acc[i][t] = (f32x4){0.f, 0.f, 0.f, 0.f};

#pragma unroll 1
    for (int tap = 0; tap < 9; ++tap) {
        const int ky = tap / 3, kx = tap % 3;
        const u16* wt = whb + ((long)h * 9 + tap) * 24576;
#pragma unroll
        for (int cs = 0; cs < 3; ++cs) {
            short8 afr[4], bfr[4];
#pragma unroll
            for (int i = 0; i < 4; ++i)
                afr[i] = *(const short8*)&r_lds[oyA[i] + ky][oxA[i] + kx][cs * 32 + q * 8];
#pragma unroll
            for (int t = 0; t < 4; ++t)
                bfr[t] = *(const short8*)(wt + ((cs << 8) + wave * 64 + t * 16 + n15) * 32 + q * 8);
#pragma unroll
            for (int i = 0; i < 4; ++i)
#pragma unroll
                for (int t = 0; t < 4; ++t)
                    acc[i][t] = __builtin_amdgcn_mfma_f32_16x16x32_bf16(
                        afr[i], bfr[t], acc[i][t], 0, 0, 0);
        }
    }

    const float* hb = par + PB_HD0 + h * 7456;
#pragma unroll
    for (int t = 0; t < 4; ++t) {
        int oc = wave * 64 + t * 16 + n15;
        float b1 = hb[oc], g = hb[256 + oc], be = hb[512 + oc];
        float m = hb[768 + oc], v = hb[1024 + oc];
        float scale = g / sqrtf(v + 1e-5f);
        float s = 0.f;
#pragma unroll
        for (int i = 0; i < 4; ++i)
#pragma unroll
            for (int r = 0; r < 4; ++r) {
                int pos = i * 16 + q * 4 + r;
                if (pos < 49)
                    s += fmaxf((acc[i][t][r] + b1 - m) * scale + be, 0.f);
            }
        s += __shfl_xor(s, 16);
        s += __shfl_xor(s, 32);
        if (q == 0) means[oc] = s / 49.f;
    }
    __syncthreads();

    int oc_out = ocArr[h];
    const float* w2 = hb + 1280;
    for (int k = wave; k < oc_out; k += 4) {
        float s = 0.f;
        for (int c = lane; c < 256; c += 64) s += means[c] * w2[k * 256 + c];
#pragma unroll
        for (int off = 32; off > 0; off >>= 1) s += __shfl_down(s, off);
        if (lane == 0)
            head_out[(long)n * 32 + offArr[h] + k] = s + w2[oc_out * 256 + k];
    }
}

// =====================================================================
// Fallback path (small ws): separate ROI-align + head reading roi_in
// =====================================================================
__global__ __launch_bounds__(256)
void kRoi(const void* __restrict__ feat, const int* __restrict__ flag,
          const float* __restrict__ boxes, const int* __restrict__ clsArr,
          const float* __restrict__ par, float* __restrict__ roi_in) {
    const int n = blockIdx.x, tid = threadIdx.x;
    const int bf = *flag;
    __shared__ int   x0s[14], x1s[14], y0s[14], y1s[14], vxs[14], vys[14];
    __shared__ float lxs[14], lys[14], cxs[7], cys[7];

    const float bx1 = boxes[n * 5 + 1], by1 = boxes[n * 5 + 2];
    const float bx2 = boxes[n * 5 + 3], by2 = boxes[n * 5 + 4];
    const int b = (int)boxes[n * 5 + 0];

    ROI_META
    __syncthreads();

    for (int t = tid; t < CIN * 49; t += 256) {
        int c = t / 49, p = t % 49, oy = p / 7, ox = p % 7;
        long fb = ((long)b * CIN + c) * HW;
        float acc = 0.f;
#pragma unroll
        for (int dy = 0; dy < 2; ++dy) {
            int sy = oy * 2 + dy;
            float ly = lys[sy]; int yA = y0s[sy], yB = y1s[sy], vy = vys[sy];
#pragma unroll
            for (int dx = 0; dx < 2; ++dx) {
                int sx = ox * 2 + dx;
                float lx = lxs[sx]; int xA = x0s[sx], xB = x1s[sx];
                float v = (1.f - ly) * (1.f - lx) * gload(feat, fb + yA * FW + xA, bf)
                        + (1.f - ly) * lx         * gload(feat, fb + yA * FW + xB, bf)
                        + ly * (1.f - lx)         * gload(feat, fb + yB * FW + xA, bf)
                        + ly * lx                 * gload(feat, fb + yB * FW + xB, bf);
                if (!(vy && vxs[sx])) v = 0.f;
                acc += v;
            }
        }
        roi_in[((long)n * CROI + c) * 49 + p] = acc * 0.25f;
    }
    int cls = clsArr[n];
    for (int t = tid; t < 5 * 49; t += 256) {
        int ch = t / 49, p = t % 49, i = p / 7, j = p % 7;
        float v;
        if (ch == 0)      v = cxs[j];
        else if (ch == 1) v = cys[i];
        else              v = (cls == ch - 2) ? 1.f : 0.f;
        roi_in[((long)n * CROI + 64 + ch) * 49 + p] = v;
    }
}

__global__ __launch_bounds__(256, 4)
void kHeadM(const float* __restrict__ roi_in, const u16* __restrict__ whb,
            const float* __restrict__ par, float* __restrict__ head_out) {
    const int h = blockIdx.x, n = blockIdx.y, tid = threadIdx.x;
    const int wave = tid >> 6, lane = tid & 63;
    const int q = lane >> 4, n15 = lane & 15;
    const int ocArr[4] = {2, 2, 4, 24};
    const int offArr[4] = {0, 2, 4, 8};
    __shared__ __align__(16) u16 r_lds[9][9][104];
    __shared__ float means[256];

    for (int i = tid; i < 9 * 9 * 104 / 8; i += 256)
        ((uint4*)r_lds)[i] = (uint4){0, 0, 0, 0};
    __syncthreads();
    const float* rp = roi_in + (long)n * CROI * 49;
    for (int i = tid; i < CROI * 49; i += 256) {
        int c = i / 49, p = i % 49;
        r_lds[p / 7 + 1][p % 7 + 1][c] = f2b(rp[i]);
    }
    __syncthreads();

    int oyA[4], oxA[4];
#pragma unroll
    for (int i = 0; i < 4; ++i) {
        int pos = i * 16 + n15; if (pos > 48) pos = 48;
        oyA[i] = pos / 7; oxA[i] = pos % 7;
    }

    f32x4 acc[4][4];
#pragma unroll
    for (int i = 0; i < 4; ++i)
#pragma unroll
        for (int t = 0; t < 4; ++t) acc[i][t] = (f32x4){0.f, 0.f, 0.f, 0.f};

#pragma unroll 1
    for (int tap = 0; tap < 9; ++tap) {
        const int ky = tap / 3, kx = tap % 3;
        const u16* wt = whb + ((long)h * 9 + tap) * 24576;
#pragma unroll
        for (int cs = 0; cs < 3; ++cs) {
            short8 afr[4], bfr[4];
#pragma unroll
            for (int i = 0; i < 4; ++i)
                afr[i] = *(const short8*)&r_lds[oyA[i] + ky][oxA[i] + kx][cs * 32 + q * 8];
#pragma unroll
            for (int t = 0; t < 4; ++t)
                bfr[t] = *(const short8*)(wt + ((cs << 8) + wave * 64 + t * 16 + n15) * 32 + q * 8);
#pragma unroll
            for (int i = 0; i < 4; ++i)
#pragma unroll
                for (int t = 0; t < 4; ++t)
                    acc[i][t] = __builtin_amdgcn_mfma_f32_16x16x32_bf16(
                        afr[i], bfr[t], acc[i][t], 0, 0, 0);
        }
    }

    const float* hb = par + PB_HD0 + h * 7456;
#pragma unroll
    for (int t = 0; t < 4; ++t) {
        int oc = wave * 64 + t * 16 + n15;
        float b1 = hb[oc], g = hb[256 + oc], be = hb[512 + oc];
        float m = hb[768 + oc], v = hb[1024 + oc];
        float scale = g / sqrtf(v + 1e-5f);
        float s = 0.f;
#pragma unroll
        for (int i = 0; i < 4; ++i)
#pragma unroll
            for (int r = 0; r < 4; ++r) {
                int pos = i * 16 + q * 4 + r;
                if (pos < 49)
                    s += fmaxf((acc[i][t][r] + b1 - m) * scale + be, 0.f);
            }
        s += __shfl_xor(s, 16);
        s += __shfl_xor(s, 32);
        if (q == 0) means[oc] = s / 49.f;
    }
    __syncthreads();

    int oc_out = ocArr[h];
    const float* w2 = hb + 1280;
    for (int k = wave; k < oc_out; k += 4) {
        float s = 0.f;
        for (int c = lane; c < 256; c += 64) s += means[c] * w2[k * 256 + c];
#pragma unroll
        for (int off = 32; off > 0; off >>= 1) s += __shfl_down(s, off);
        if (lane == 0)
            head_out[(long)n * 32 + offArr[h] + k] = s + w2[oc_out * 256 + k];
    }
}

// =====================================================================
// Final scalar math + small outputs
// =====================================================================
__global__ void kFinal(const float* __restrict__ head_out, const float* __restrict__ boxes,
                       const int* __restrict__ clsArr, const float* __restrict__ par,
                       void* __restrict__ out, const int* __restrict__ flag) {
    int n = blockIdx.x * 256 + threadIdx.x;
    if (n >= NROI) return;
    const int bf = *flag;
    const float* ho = head_out + (long)n * 32;
    float dep0 = ho[0], dep1 = ho[1];
    int b = (int)boxes[n * 5 + 0];
    int cls = clsArr[n];

    for (int j = 0; j < 24; ++j) gstore(out, O_HEAD + n * 24 + j, ho[8 + j], bf);
    gstore(out, O_OFF3 + n * 2 + 0, ho[2], bf);
    gstore(out, O_OFF3 + n * 2 + 1, ho[3], bf);
    gstore(out, O_S3D + n * 3 + 0, ho[4], bf);
    gstore(out, O_S3D + n * 3 + 1, ho[5], bf);
    gstore(out, O_S3D + n * 3 + 2, ho[6], bf);
    gstore(out, O_H3D + n, ho[7], bf);

    float cry0 = par[PB_CRN + b * 4 + 1], cry1 = par[PB_CRN + b * 4 + 3];
    float sy = cry1 - cry0;
    float bi2 = boxes[n * 5 + 2] / (float)FH * sy + cry0;
    float bi4 = boxes[n * 5 + 4] / (float)FH * sy + cry0;
    float box_h = fmaxf(bi4 - bi2, 1.f);
    float f_u = par[PB_CAL + b * 12 + 0];
    float size3d0 = par[PB_MSZ + cls * 3 + 0] + ho[4];
    float depth_geo = size3d0 / box_h * f_u;
    float sig = 1.f / (1.f + expf(-dep0));
    float d0 = 1.f / (sig + 1e-6f) - 1.f + depth_geo;
    float dgls = ho[7] + 2.f * (logf(f_u) - logf(box_h));
    float mx = fmaxf(dep1, dgls);
    float lse = mx + logf(expf(dep1 - mx) + expf(dgls - mx));
    gstore(out, O_DEP + n * 2 + 0, d0, bf);
    gstore(out, O_DEP + n * 2 + 1, lse, bf);
}

// =====================================================================
extern "C" void kernel_launch(void* const* d_in, const int* in_sizes, int n_in,
                              void* d_out, int out_size, void* d_ws, size_t ws_size,
                              hipStream_t stream) {
    (void)in_sizes; (void)n_in; (void)out_size;
    float* ws = (float*)d_ws;
    float* par = ws + WS_PAR;
    int* flag = (int*)(ws + WS_FLAG);
    u16* wb16 = (u16*)(ws + WS_WB16);
    u16* whb  = (u16*)(ws + WS_W1H);
    u16* featT = (u16*)(ws + WS_FEATT);
    const void* feat = d_in[0];
    const bool bigws = ws_size >= (size_t)WS_END * 4;

    WPtrs WP;
    WP.bw[0] = d_in[4]; WP.bw[1] = d_in[8]; WP.bw[2] = d_in[12];
    WP.hw[0] = d_in[16]; WP.hw[1] = d_in[24]; WP.hw[2] = d_in[32]; WP.hw[3] = d_in[40];

    Segs SG; int si = 0;
    auto add = [&](const void* s, int n, int dst) {
        SG.s[si].src = s; SG.s[si].n = n; SG.s[si].dst = dst; ++si;
    };
    add(d_in[1], 96, PB_CAL); add(d_in[2], 32, PB_CRN); add(d_in[3], 9, PB_MSZ);
    const int ocb[3] = {3, 2, 2};
    for (int b = 0; b < 3; ++b) {
        int base = PB_BR0 + b * 1040;
        int i0 = 4 + 4 * b;
        add(d_in[i0 + 1], 256, base);
        add(d_in[i0 + 2], ocb[b] * 256, base + 256);
        add(d_in[i0 + 3], ocb[b], base + 256 + ocb[b] * 256);
    }
    const int och[4] = {2, 2, 4, 24};
    for (int h = 0; h < 4; ++h) {
        int base = PB_HD0 + h * 7456;
        int i0 = 16 + 8 * h;
        add(d_in[i0 + 1], 256, base);
        add(d_in[i0 + 2], 256, base + 256);
        add(d_in[i0 + 3], 256, base + 512);
        add(d_in[i0 + 4], 256, base + 768);
        add(d_in[i0 + 5], 256, base + 1024);
        add(d_in[i0 + 6], och[h] * 256, base + 1280);
        add(d_in[i0 + 7], och[h], base + 1280 + och[h] * 256);
    }
    SG.cnt = si;

    kPrepWP<<<5760 + 40, 256, 0, stream>>>(WP, SG, feat, flag,
                                           ws + WS_W1T, wb16, whb, par);

    // mega dispatch: long-pole roles first (z=0 strip, z=1 transpose),
    // conv at z=2..9 -- blocks dispatch x->y->z so strip/transpose overlap conv
    kBranch3M<<<dim3(5, 48, 10), 512, 0, stream>>>(
        feat, flag, wb16, par + PB_BR0, ws + WS_W1T, d_out, ws, bigws ? 1 : 0);

    kNmsTopA<<<dim3(24, NCHUNK), 256, 0, stream>>>(ws + WS_HEAT, ws + WS_NH);
    kTopBC<<<8, 192, 0, stream>>>(ws + WS_NH, ws + WS_OFF2, ws + WS_SIZ2,
                                  ws + WS_BOX, (int*)(ws + WS_CLS));
    if (bigws) {
        kHeadM2<<<dim3(4, NROI), 256, 0, stream>>>(featT, ws + WS_BOX,
                                                   (int*)(ws + WS_CLS), whb, par,
                                                   ws + WS_HOUT);
    } else {
        kRoi<<<400, 256, 0, stream>>>(feat, flag, ws + WS_BOX, (int*)(ws + WS_CLS),
                                      par, ws + WS_ROI);
        kHeadM<<<dim3(4, NROI), 256, 0, stream>>>(ws + WS_ROI, whb, par, ws + WS_HOUT);
    }
    kFinal<<<2, 256, 0, stream>>>(ws + WS_HOUT, ws + WS_BOX, (int*)(ws + WS_CLS),
                                  par, d_out, flag);
}

// Round 8
// 748.348 us; speedup vs baseline: 1.1241x; 1.0082x over previous
//
#include <hip/hip_runtime.h>
#include <math.h>

typedef unsigned short u16;
typedef unsigned int   u32;
typedef unsigned long long u64;
typedef __attribute__((ext_vector_type(8))) short short8;   // 8 bf16 (4 VGPR)
typedef __attribute__((ext_vector_type(4))) float f32x4;    // MFMA acc

// ---------- dtype helpers ----------
__device__ __forceinline__ float b2f(u16 v) { return __uint_as_float(((u32)v) << 16); }
__device__ __forceinline__ u16 f2b(float f) {
    u32 u = __float_as_uint(f);
    u32 r = (u + 0x7FFFu + ((u >> 16) & 1u)) >> 16;   // RNE
    return (u16)r;
}
__device__ __forceinline__ float gload(const void* p, long i, int bf) {
    return bf ? b2f(((const u16*)p)[i]) : ((const float*)p)[i];
}
__device__ __forceinline__ void gstore(void* p, long i, float v, int bf) {
    if (bf) ((u16*)p)[i] = f2b(v);
    else    ((float*)p)[i] = v;
}

// top-k key: smallest key = (largest value, then smallest index)
__device__ __forceinline__ u64 packKey(float v, int idx) {
    u32 u = __float_as_uint(v);
    u32 m = (u & 0x80000000u) ? ~u : (u | 0x80000000u);   // monotone float->uint
    return ((u64)(~m) << 32) | (u32)idx;
}

// per-block dtype-flag recompute (512 u16 probe of feat)
__device__ int blockFlag(const void* feat) {
    __shared__ int fcnt;
    if (threadIdx.x == 0) fcnt = 0;
    __syncthreads();
    int sane = 0;
    for (int i = threadIdx.x; i < 512; i += blockDim.x) {
        u16 v = ((const u16*)feat)[i];
        float f = b2f(v);
        u32 e = (v >> 7) & 0xFF;
        float a = fabsf(f);
        sane += (e != 0xFF) && (f == 0.f || (a >= 1e-8f && a <= 1e4f));
    }
    atomicAdd(&fcnt, sane);
    __syncthreads();
    return fcnt >= 480;
}

// ---------- problem constants ----------
#define BATCH 8
#define CIN   64
#define FH    96
#define FW    320
#define KDET  50
#define NROI  400
#define CROI  69
#define HW    (FH*FW)
#define CHUNK 1920
#define NCHUNK 16

// ---------- workspace layout (float offsets) ----------
#define WS_HEAT 0L
#define WS_OFF2 737280L
#define WS_SIZ2 1228800L
#define WS_NH   1720320L
#define WS_CLS  2460000L
#define WS_BOX  2460400L
#define WS_ROI  2462400L
#define WS_HOUT 3814800L
#define WS_W1T  3827600L     // 147456 f32: hm conv1 [k=576][c=256] (exact strip)
#define WS_WB16 3975056L     // u16: 3 branches * [9][2][256][32] bf16 (lane-coalesced)
#define WS_W1H  4269968L     // u16: 4 heads * [9][3][256][32] bf16
#define WS_PAR  4905872L     // packed f32 params
#define WS_FLAG 4938960L     // int dtype flag
#define WS_FEATT 4938964L    // u16: [8][96][320][64] bf16 transposed features
#define WS_END  (WS_FEATT + 7864320L)

// param block sub-offsets
#define PB_CAL 0
#define PB_CRN 96
#define PB_MSZ 128
#define PB_BR0 144          // stride 1040: b1@0, w2@256 ([k][n]), b2@256+OC*256
#define PB_HD0 3264         // stride 7456

// ---------- output layout (element offsets) ----------
#define O_HEAT 0L
#define O_OFF2 737280L
#define O_SIZ2 1228800L
#define O_HEAD 1720320L
#define O_DEP  1729920L
#define O_OFF3 1730720L
#define O_S3D  1731520L
#define O_H3D  1732720L

// =====================================================================
// Fused prep: weights + params + flag
// =====================================================================
struct WPtrs { const void* bw[3]; const void* hw[4]; };
struct Seg { const void* src; int n; int dst; };
struct Segs { Seg s[40]; int cnt; };

__global__ void kPrepWP(WPtrs P, Segs S, const void* __restrict__ feat,
                        int* __restrict__ flag, float* __restrict__ w1t,
                        u16* __restrict__ wb16, u16* __restrict__ whb,
                        float* __restrict__ par) {
    const int bf = blockFlag(feat);
    if (blockIdx.x == 0 && threadIdx.x == 0) *flag = bf;
    if (blockIdx.x < 5760) {
        int idx = blockIdx.x * 256 + threadIdx.x;
        if (idx < 147456) {
            int k = idx >> 8, c = idx & 255;
            w1t[idx] = gload(P.bw[0], (long)c * 576 + k, bf);
        } else if (idx < 589824) {
            int j = idx - 147456;
            int br = j / 147456, rem = j % 147456;
            int tap = rem / 16384;
            int r2 = rem & 16383;
            int s = r2 >> 13;
            int n = (r2 >> 5) & 255;
            int c5 = r2 & 31;
            int ci = s * 32 + c5;
            wb16[j] = f2b(gload(P.bw[br], (long)n * 576 + ci * 9 + tap, bf));
        } else {
            int j = idx - 589824;               // < 884736
            int h = j / 221184, rem = j % 221184;
            int tap = rem / 24576, rem2 = rem % 24576;
            int cs = rem2 / 8192, rem3 = rem2 % 8192;
            int oc = rem3 >> 5, jj = rem3 & 31;
            int ci = cs * 32 + jj;
            u16 val = 0;
            if (ci < CROI) val = f2b(gload(P.hw[h], (long)oc * 621 + ci * 9 + tap, bf));
            whb[j] = val;
        }
    } else {
        int sidx = blockIdx.x - 5760;
        if (sidx < S.cnt) {
            Seg sg = S.s[sidx];
            for (int i = threadIdx.x; i < sg.n; i += 256)
                par[sg.dst + i] = gload(sg.src, i, bf);
        }
    }
}

// =====================================================================
// Mega branch dispatch: grid (5, 48, 8/9/10)
//   z<8  : MFMA conv role (b=z); heat stores skip rows 0..2
//   z==8 : exact f32 strip role (heat rows 0..2)
//   z==9 : feature transpose role (only launched when bigws)
// =====================================================================
union MLds {
    struct { u16 a[4][68][72]; float red[8][64][3]; } c;
    struct {
        float in[4][3][36];
        union { float w[36 * 256]; float part[32 * 3 * 32]; } u;
    } s;
    u16 t[64][72];
};

__global__ __launch_bounds__(512, 4)
void kBranch3M(const void* __restrict__ feat, const int* __restrict__ flag,
               const u16* __restrict__ wbAll,   // 3 * [9][2][256][32] bf16
               const float* __restrict__ bpAll, // par + PB_BR0, stride 1040
               const float* __restrict__ w1t,   // strip weights f32
               void* __restrict__ outb, float* __restrict__ wsbase) {
    __shared__ __align__(16) MLds L;

    const long obase[3] = {O_HEAT, O_OFF2, O_SIZ2};
    const long wfs[3]   = {WS_HEAT, WS_OFF2, WS_SIZ2};

    const int bfl = *flag;
    const int tid = threadIdx.x;

    if (blockIdx.z == 9) {
        // ================= TRANSPOSE ROLE: [b][c][h][w]->[b][h][w][c] ==
        u16* featT = (u16*)(wsbase + WS_FEATT);
        const int x0 = blockIdx.x * 64;
        const int y0 = blockIdx.y * 2;
        for (int sub = 0; sub < 16; ++sub) {       // 8 b x 2 rows
            const int b = sub >> 1, y = y0 + (sub & 1);
            __syncthreads();
            for (int i = tid; i < 64 * 64; i += 512) {
                int c = i >> 6, x = i & 63;        // lanes: consecutive x
                L.t[x][c] = f2b(gload(feat, ((long)(b * CIN + c) * FH + y) * FW + x0 + x, bfl));
            }
            __syncthreads();
            u16* outp = featT + (((long)b * FH + y) * FW + x0) * 64;
            for (int i = tid; i < 64 * 64; i += 512) {
                int x = i >> 6, c = i & 63;        // lanes: consecutive c
                outp[(long)x * 64 + c] = L.t[x][c];
            }
        }
        return;
    }

    if (blockIdx.z == 8) {
        // ================= STRIP ROLE (exact f32, rows 0..2) ==========
        const int sidx = blockIdx.y * 5 + blockIdx.x;   // 0..239
        const int x0 = (sidx % 10) * 32;
        const int srem = sidx / 10;
        const int y = srem % 3;
        const int b = srem / 3;
        const float* bp = bpAll;                        // heat branch params
        const int OC = 3;
        const int xg = tid & 7, cg = tid >> 3;
        const int c0 = (cg & 31) * 8;

        float acc[8][4];
#pragma unroll
        for (int i = 0; i < 8; ++i)
#pragma unroll
            for (int j = 0; j < 4; ++j) acc[i][j] = 0.f;

        for (int chunk = 0; chunk < 16; ++chunk) {
            const int ci0 = chunk * 4;
            __syncthreads();
            for (int i = tid; i < 4 * 3 * 36; i += 512) {
                int xx = i % 36, t2 = i / 36;
                int r = t2 % 3, ci = t2 / 3;
                int gx = x0 - 1 + xx, gy = y - 1 + r;
                float v = 0.f;
                if (gx >= 0 && gx < FW && gy >= 0 && gy < FH)
                    v = gload(feat, ((long)(b * CIN + ci0 + ci) * FH + gy) * FW + gx, bfl);
                L.s.in[ci][r][xx] = v;
            }
            {
                const float4* src = (const float4*)(w1t + (long)ci0 * 9 * 256);
                float4* dst = (float4*)L.s.u.w;
                for (int i = tid; i < 36 * 256 / 4; i += 512) dst[i] = src[i];
            }
            __syncthreads();
            if (tid < 256) {
#pragma unroll
                for (int ci = 0; ci < 4; ++ci) {
#pragma unroll
                    for (int ky = 0; ky < 3; ++ky) {
                        const float* rowp = &L.s.in[ci][ky][xg * 4];
                        float inv[6];
                        *(float4*)&inv[0] = *(const float4*)&rowp[0];
                        *(float2*)&inv[4] = *(const float2*)&rowp[4];
#pragma unroll
                        for (int kx = 0; kx < 3; ++kx) {
                            const float* wp = &L.s.u.w[(ci * 9 + ky * 3 + kx) * 256 + c0];
                            float wv[8];
                            *(float4*)&wv[0] = *(const float4*)&wp[0];
                            *(float4*)&wv[4] = *(const float4*)&wp[4];
#pragma unroll
                            for (int cc = 0; cc < 8; ++cc)
#pragma unroll
                                for (int xx = 0; xx < 4; ++xx)
                                    acc[cc][xx] = fmaf(wv[cc], inv[xx + kx], acc[cc][xx]);
                        }
                    }
                }
            }
        }

        if (tid < 256) {
#pragma unroll
            for (int cc = 0; cc < 8; ++cc) {
                float b1v = bp[c0 + cc];
#pragma unroll
                for (int xx = 0; xx < 4; ++xx)
                    acc[cc][xx] = fmaxf(acc[cc][xx] + b1v, 0.f);
            }
        }
        __syncthreads();
        if (tid < 256) {
#pragma unroll
            for (int k = 0; k < OC; ++k) {
                float p[4];
#pragma unroll
                for (int xx = 0; xx < 4; ++xx) p[xx] = 0.f;
#pragma unroll
                for (int cc = 0; cc < 8; ++cc) {
                    float wv = bp[256 + k * 256 + c0 + cc];
#pragma unroll
                    for (int xx = 0; xx < 4; ++xx) p[xx] = fmaf(acc[cc][xx], wv, p[xx]);
                }
#pragma unroll
                for (int xx = 0; xx < 4; ++xx)
                    L.s.u.part[((cg & 31) * OC + k) * 32 + xg * 4 + xx] = p[xx];
            }
        }
        __syncthreads();
        float* outf = wsbase + WS_HEAT;
        for (int t = tid; t < OC * 32; t += 512) {
            int k = t >> 5, xx = t & 31;
            float s = bp[256 + OC * 256 + k];
#pragma unroll 8
            for (int g = 0; g < 32; ++g) s += L.s.u.part[(g * OC + k) * 32 + xx];
            long o = (((long)b * OC + k) * FH + y) * FW + x0 + xx;
            gstore(outb, O_HEAT + o, s, bfl);
            outf[o] = s;
        }
        return;
    }

    // ==================== CONV ROLE (MFMA) ============================
    const int wave = tid >> 6, lane = tid & 63;
    const int q = lane >> 4, n15 = lane & 15;
    const int mg = wave >> 2, ng = wave & 3;
    const int x0 = blockIdx.x * 64, y0 = blockIdx.y * 2;
    const int b = blockIdx.z;

    if (tid < 256) {
        const int ci = tid & 63, rr = tid >> 6;
        const int gy = y0 - 1 + rr;
        if (gy < 0 || gy >= FH) {
            for (int xi = 0; xi < 66; ++xi) L.c.a[rr][xi][ci] = 0;
        } else if (bfl) {
            const u16* rp = (const u16*)feat + ((long)((b << 6) | ci) * FH + gy) * FW;
            for (int j = 0; j < 10; ++j) {
                int xs0 = x0 - 8 + j * 8;
                u16 tmp[8];
                if (xs0 >= 0 && xs0 <= FW - 8)
                    *(uint4*)tmp = *(const uint4*)(rp + xs0);
                else
                    for (int e = 0; e < 8; ++e) {
                        int gx = xs0 + e;
                        tmp[e] = (gx >= 0 && gx < FW) ? rp[gx] : (u16)0;
                    }
                for (int e = 0; e < 8; ++e) {
                    int xi = xs0 + e - x0 + 1;
                    if (xi >= 0 && xi < 66) L.c.a[rr][xi][ci] = tmp[e];
                }
            }
        } else {
            const float* rp = (const float*)feat + ((long)((b << 6) | ci) * FH + gy) * FW;
            for (int j = 0; j < 18; ++j) {
                int xs0 = x0 - 4 + j * 4;
                float tmp[4];
                if (xs0 >= 0 && xs0 <= FW - 4)
                    *(float4*)tmp = *(const float4*)(rp + xs0);
                else
                    for (int e = 0; e < 4; ++e) {
                        int gx = xs0 + e;
                        tmp[e] = (gx >= 0 && gx < FW) ? rp[gx] : 0.f;
                    }
                for (int e = 0; e < 4; ++e) {
                    int xi = xs0 + e - x0 + 1;
                    if (xi >= 0 && xi < 66) L.c.a[rr][xi][ci] = f2b(tmp[e]);
                }
            }
        }
    }
    __syncthreads();   // a_lds visible; read-only from here on

#pragma unroll 1
    for (int br = 0; br < 3; ++br) {
        const int oc = (br == 0) ? 3 : 2;
        const u16* wpt = wbAll + br * 147456;
        const float* bp = bpAll + br * 1040;

        f32x4 acc[4][4];
#pragma unroll
        for (int i = 0; i < 4; ++i)
#pragma unroll
            for (int t = 0; t < 4; ++t) acc[i][t] = (f32x4){0.f, 0.f, 0.f, 0.f};

#pragma unroll 1
        for (int tap = 0; tap < 9; ++tap) {
            const int ky = tap / 3, kx = tap % 3;
#pragma unroll
            for (int s = 0; s < 2; ++s) {
                const u16* wks = wpt + (tap * 2 + s) * 8192;
                short8 bfr[4];
#pragma unroll
                for (int t = 0; t < 4; ++t)
                    bfr[t] = *(const short8*)(wks + (ng * 64 + t * 16 + n15) * 32 + q * 8);
                short8 afr[4];
#pragma unroll
                for (int i = 0; i < 4; ++i)
                    afr[i] = *(const short8*)&L.c.a[mg + ky][i * 16 + n15 + kx][s * 32 + q * 8];
#pragma unroll
                for (int i = 0; i < 4; ++i)
#pragma unroll
                    for (int t = 0; t < 4; ++t)
                        acc[i][t] = __builtin_amdgcn_mfma_f32_16x16x32_bf16(
                            afr[i], bfr[t], acc[i][t], 0, 0, 0);
            }
        }

        float b1v[4], w2v[3][4];
#pragma unroll
        for (int t = 0; t < 4; ++t) {
            int n = ng * 64 + t * 16 + n15;
            b1v[t] = bp[n];
#pragma unroll
            for (int k = 0; k < 3; ++k) w2v[k][t] = bp[256 + k * 256 + n];
        }
        __syncthreads();
#pragma unroll
        for (int i = 0; i < 4; ++i) {
#pragma unroll
            for (int r = 0; r < 4; ++r) {
                float pk[3];
#pragma unroll
                for (int k = 0; k < 3; ++k) pk[k] = 0.f;
#pragma unroll
                for (int t = 0; t < 4; ++t) {
                    float h = fmaxf(acc[i][t][r] + b1v[t], 0.f);
#pragma unroll
                    for (int k = 0; k < 3; ++k) pk[k] = fmaf(h, w2v[k][t], pk[k]);
                }
#pragma unroll
                for (int k = 0; k < 3; ++k) {
                    pk[k] += __shfl_xor(pk[k], 1);
                    pk[k] += __shfl_xor(pk[k], 2);
                    pk[k] += __shfl_xor(pk[k], 4);
                    pk[k] += __shfl_xor(pk[k], 8);
                }
                if (n15 == 0) {
                    int ml = i * 16 + q * 4 + r;
#pragma unroll
                    for (int k = 0; k < 3; ++k) L.c.red[wave][ml][k] = pk[k];
                }
            }
        }
        __syncthreads();
        float* outf = wsbase + wfs[br];
        for (int t2 = tid; t2 < oc * 128; t2 += 512) {
            int k = t2 >> 7, m = t2 & 127;
            int row = m >> 6, x = m & 63;
            int mg2 = m >> 6, ml = m & 63;
            float s = bp[256 + oc * 256 + k];
#pragma unroll
            for (int w = 0; w < 4; ++w) s += L.c.red[mg2 * 4 + w][ml][k];
            int grow = y0 + row;
            if (br == 0 && grow < 3) continue;    // strip role owns heat rows 0..2
            long o = (((long)b * oc + k) * FH + grow) * FW + x0 + x;
            gstore(outb, obase[br] + o, s, bfl);
            outf[o] = s;
        }
    }
}

// =====================================================================
// Fused NMS + top-k stage A (4-wave hierarchical extraction)
// =====================================================================
__global__ __launch_bounds__(256)
void kNmsTopA(const float* __restrict__ heat, float* __restrict__ nh) {
    __shared__ float hrow[8][320];
    __shared__ u64 keys[CHUNK];
    __shared__ u64 sub[4][KDET];
    const int bc = blockIdx.x, ch = blockIdx.y;
    const int tid = threadIdx.x;
    const int wave = tid >> 6, lane = tid & 63;
    const int r0 = ch * 6;
    const float* hp = heat + (long)bc * HW;

    for (int i = tid; i < 8 * 320; i += 256) {
        int rr = i / 320, x = i % 320;
        int gy = r0 - 1 + rr;
        hrow[rr][x] = (gy >= 0 && gy < FH) ? hp[(long)gy * FW + x] : -INFINITY;
    }
    __syncthreads();
    for (int i = tid; i < CHUNK; i += 256) {
        int ry = i / 320, x = i % 320;
        float v = hrow[ry + 1][x];
        float m = v;
        int xm = max(x - 1, 0), xp = min(x + 1, FW - 1);
#pragma unroll
        for (int dy = 0; dy < 3; ++dy) {
            m = fmaxf(m, hrow[ry + dy][xm]);
            m = fmaxf(m, hrow[ry + dy][x]);
            m = fmaxf(m, hrow[ry + dy][xp]);
        }
        float nv = (v == m) ? v : 0.f;
        keys[i] = packKey(nv, ch * CHUNK + i);
    }
    __syncthreads();
    // each wave: top-50 of its 480-element sub-chunk
    {
        u64* kw = keys + wave * 480;
        for (int it = 0; it < KDET; ++it) {
            u64 bk = ~0ULL; int bp = 0;
            for (int i = lane; i < 480; i += 64) {
                u64 k = kw[i];
                if (k < bk) { bk = k; bp = i; }
            }
#pragma unroll
            for (int s = 32; s > 0; s >>= 1) {
                u64 k2 = __shfl_down(bk, s);
                int p2 = __shfl_down(bp, s);
                if (k2 < bk) { bk = k2; bp = p2; }
            }
            bk = __shfl(bk, 0);
            bp = __shfl(bp, 0);
            if (lane == 0) {
                sub[wave][it] = bk;
                kw[bp] = ~0ULL;
            }
        }
    }
    __syncthreads();
    // wave 0: merge 4x50 -> chunk top-50
    if (wave == 0) {
        u64* outp = (u64*)(nh + (long)bc * HW + (long)ch * CHUNK);
        u64* sp = &sub[0][0];
        for (int it = 0; it < KDET; ++it) {
            u64 bk = ~0ULL; int bp = 0;
            for (int i = lane; i < 4 * KDET; i += 64) {
                u64 k = sp[i];
                if (k < bk) { bk = k; bp = i; }
            }
#pragma unroll
            for (int s = 32; s > 0; s >>= 1) {
                u64 k2 = __shfl_down(bk, s);
                int p2 = __shfl_down(bp, s);
                if (k2 < bk) { bk = k2; bp = p2; }
            }
            bk = __shfl(bk, 0);
            bp = __shfl(bp, 0);
            if (lane == 0) {
                outp[it] = bk;
                sp[bp] = ~0ULL;
            }
        }
    }
}

// =====================================================================
// Fused top-k stage B + stage 2 + boxes
// =====================================================================
__global__ __launch_bounds__(192)
void kTopBC(const float* __restrict__ nh, const float* __restrict__ off2,
            const float* __restrict__ siz2, float* __restrict__ boxes,
            int* __restrict__ clsArr) {
    __shared__ u64 keys[3][NCHUNK * KDET];
    __shared__ float sc[150];
    __shared__ int   si[150];
    const int b = blockIdx.x, tid = threadIdx.x;
    const int wave = tid >> 6, lane = tid & 63;
    const int bc = b * 3 + wave;

    for (int ch = 0; ch < NCHUNK; ++ch) {
        const u64* src = (const u64*)(nh + (long)bc * HW + (long)ch * CHUNK);
        if (lane < KDET) keys[wave][ch * KDET + lane] = src[lane];
    }
    __syncthreads();
    for (int it = 0; it < KDET; ++it) {
        u64 bk = ~0ULL; int bp = 0;
        for (int i = lane; i < NCHUNK * KDET; i += 64) {
            u64 k = keys[wave][i];
            if (k < bk) { bk = k; bp = i; }
        }
#pragma unroll
        for (int s = 32; s > 0; s >>= 1) {
            u64 k2 = __shfl_down(bk, s);
            int p2 = __shfl_down(bp, s);
            if (k2 < bk) { bk = k2; bp = p2; }
        }
        bk = __shfl(bk, 0);
        bp = __shfl(bp, 0);
        if (lane == 0) {
            u32 hm = ~(u32)(bk >> 32);
            u32 u = (hm & 0x80000000u) ? (hm & 0x7fffffffu) : ~hm;
            sc[wave * KDET + it] = __uint_as_float(u);
            si[wave * KDET + it] = (int)(bk & 0xFFFFFFFFu);
            keys[wave][bp] = ~0ULL;
        }
    }
    __syncthreads();
    if (wave == 0) {
        const int t = lane;
        for (int r = 0; r < KDET; ++r) {
            float bv = -INFINITY; int bp = 0x7fffffff;
            for (int i = t; i < 150; i += 64) {
                float v = sc[i];
                if (v > bv) { bv = v; bp = i; }
            }
#pragma unroll
            for (int s = 32; s > 0; s >>= 1) {
                float v2 = __shfl_down(bv, s);
                int   p2 = __shfl_down(bp, s);
                if (v2 > bv || (v2 == bv && p2 < bp)) { bv = v2; bp = p2; }
            }
            bp = __shfl(bp, 0);
            if (t == 0) {
                int cls = bp / KDET;
                int ind = si[bp];
                int n = b * KDET + r;
                clsArr[n] = cls;
                int x = ind % FW, yy = ind / FW;
                float cx = (float)x  + off2[(((long)b * 2 + 0) * FH + yy) * FW + x];
                float cy = (float)yy + off2[(((long)b * 2 + 1) * FH + yy) * FW + x];
                float w  = siz2[(((long)b * 2 + 0) * FH + yy) * FW + x];
                float h  = siz2[(((long)b * 2 + 1) * FH + yy) * FW + x];
                boxes[n * 5 + 0] = (float)b;
                boxes[n * 5 + 1] = cx - w * 0.5f;
                boxes[n * 5 + 2] = cy - h * 0.5f;
                boxes[n * 5 + 3] = cx + w * 0.5f;
                boxes[n * 5 + 4] = cy + h * 0.5f;
                sc[bp] = -INFINITY;
            }
        }
    }
}

// =====================================================================
// ROI metadata helper
// =====================================================================
#define ROI_META \
    if (tid < 14) { \
        float roi_w = fmaxf(bx2 - bx1, 1.f); \
        float X = bx1 + (roi_w / 7.f) * ((tid + 0.5f) * 0.5f); \
        vxs[tid] = (X > -1.f) && (X < (float)FW); \
        float Xc = fminf(fmaxf(X, 0.f), (float)(FW - 1)); \
        int xi = (int)floorf(Xc); \
        x0s[tid] = xi; x1s[tid] = min(xi + 1, FW - 1); lxs[tid] = Xc - (float)xi; \
    } else if (tid >= 16 && tid < 30) { \
        int i = tid - 16; \
        float roi_h = fmaxf(by2 - by1, 1.f); \
        float Y = by1 + (roi_h / 7.f) * ((i + 0.5f) * 0.5f); \
        vys[i] = (Y > -1.f) && (Y < (float)FH); \
        float Yc = fminf(fmaxf(Y, 0.f), (float)(FH - 1)); \
        int yi = (int)floorf(Yc); \
        y0s[i] = yi; y1s[i] = min(yi + 1, FH - 1); lys[i] = Yc - (float)yi; \
    } else if (tid >= 32 && tid < 46) { \
        int j = tid - 32; \
        const float* cal = par + PB_CAL + b * 12; \
        float f_u = cal[0], c_u = cal[2], t03 = cal[3]; \
        float f_v = cal[5], c_v = cal[6], t13 = cal[7]; \
        float bxc = t03 / (-f_u), byc = t13 / (-f_v); \
        const float* cr = par + PB_CRN + b * 4; \
        float crx0 = cr[0], cry0 = cr[1], crx1 = cr[2], cry1 = cr[3]; \
        float sx = crx1 - crx0, sy = cry1 - cry0; \
        float u1 = bx1 / (float)FW * sx + crx0, v1 = by1 / (float)FH * sy + cry0; \
        float u2 = bx2 / (float)FW * sx + crx0, v2 = by2 / (float)FH * sy + cry0; \
        float p1x = (u1 - c_u) / f_u + bxc, p1y = (v1 - c_v) / f_v + byc; \
        float p2x = (u2 - c_u) / f_u + bxc, p2y = (v2 - c_v) / f_v + byc; \
        if (j < 7) cxs[j] = p1x + ((float)j / 6.f) * (p2x - p1x); \
        else       cys[j - 7] = p1y + ((float)(j - 7) / 6.f) * (p2y - p1y); \
    }

// =====================================================================
// Fused ROI-align + MFMA head (bigws path): stages r_lds directly from
// transposed features (coalesced corners), then conv+BN+mean+1x1.
// =====================================================================
__global__ __launch_bounds__(256, 4)
void kHeadM2(const u16* __restrict__ featT, const float* __restrict__ boxes,
             const int* __restrict__ clsArr, const u16* __restrict__ whb,
             const float* __restrict__ par, float* __restrict__ head_out) {
    const int h = blockIdx.x, n = blockIdx.y, tid = threadIdx.x;
    const int wave = tid >> 6, lane = tid & 63;
    const int q = lane >> 4, n15 = lane & 15;
    const int ocArr[4] = {2, 2, 4, 24};
    const int offArr[4] = {0, 2, 4, 8};
    __shared__ __align__(16) u16 r_lds[9][9][104];
    __shared__ float means[256];
    __shared__ int   x0s[14], x1s[14], y0s[14], y1s[14], vxs[14], vys[14];
    __shared__ float lxs[14], lys[14], cxs[7], cys[7];

    const float bx1 = boxes[n * 5 + 1], by1 = boxes[n * 5 + 2];
    const float bx2 = boxes[n * 5 + 3], by2 = boxes[n * 5 + 4];
    const int b = (int)boxes[n * 5 + 0];
    ROI_META

    for (int i = tid; i < 9 * 9 * 104 / 8; i += 256)
        ((uint4*)r_lds)[i] = (uint4){0, 0, 0, 0};
    __syncthreads();

    const u16* fb = featT + (long)b * FH * FW * 64;
    for (int t = tid; t < CIN * 49; t += 256) {
        int c = t & 63, p = t >> 6;        // lanes: consecutive c (coalesced)
        int oy = p / 7, ox = p % 7;
        float acc = 0.f;
#pragma unroll
        for (int dy = 0; dy < 2; ++dy) {
            int sy = oy * 2 + dy;
            float ly = lys[sy]; int yA = y0s[sy], yB = y1s[sy], vy = vys[sy];
#pragma unroll
            for (int dx = 0; dx < 2; ++dx) {
                int sx = ox * 2 + dx;
                float lx = lxs[sx]; int xA = x0s[sx], xB = x1s[sx];
                float v = (1.f - ly) * (1.f - lx) * b2f(fb[((long)yA * FW + xA) * 64 + c])
                        + (1.f - ly) * lx         * b2f(fb[((long)yA * FW + xB) * 64 + c])
                        + ly * (1.f - lx)         * b2f(fb[((long)yB * FW + xA) * 64 + c])
                        + ly * lx                 * b2f(fb[((long)yB * FW + xB) * 64 + c]);
                if (!(vy && vxs[sx])) v = 0.f;
                acc += v;
            }
        }
        r_lds[oy + 1][ox + 1][c] = f2b(acc * 0.25f);
    }
    {
        int cls = clsArr[n];
        for (int t = tid; t < 5 * 49; t += 256) {
            int ch = t / 49, p = t % 49, i = p / 7, j = p % 7;
            float v;
            if (ch == 0)      v = cxs[j];
            else if (ch == 1) v = cys[i];
            else              v = (cls == ch - 2) ? 1.f : 0.f;
            r_lds[i + 1][j + 1][64 + ch] = f2b(v);
        }
    }
    __syncthreads();

    int oyA[4], oxA[4];
#pragma unroll
    for (int i = 0; i < 4; ++i) {
        int pos = i * 16 + n15; if (pos > 48) pos = 48;
        oyA[i] = pos / 7; oxA[i] = pos % 7;
    }

    f32x4 acc[4][4];
#pragma unroll
    for (int i = 0; i < 4; ++i)
#pragma unroll
        for (int t = 0; t < 4; ++t) acc[i][t] = (f32x4){0.f, 0.f, 0.f, 0.f};

#pragma unroll 1
    for (int tap = 0; tap < 9; ++tap) {
        const int ky = tap / 3, kx = tap % 3;
        const u16* wt = whb + ((long)h * 9 + tap) * 24576;
#pragma unroll
        for (int cs = 0; cs < 3; ++cs) {
            short8 afr[4], bfr[4];
#pragma unroll
            for (int i = 0; i < 4; ++i)
                afr[i] = *(const short8*)&r_lds[oyA[i] + ky][oxA[i] + kx][cs * 32 + q * 8];
#pragma unroll
            for (int t = 0; t < 4; ++t)
                bfr[t] = *(const short8*)(wt + ((cs << 8) + wave * 64 + t * 16 + n15) * 32 + q * 8);
#pragma unroll
            for (int i = 0; i < 4; ++i)
#pragma unroll
                for (int t = 0; t < 4; ++t)
                    acc[i][t] = __builtin_amdgcn_mfma_f32_16x16x32_bf16(
                        afr[i], bfr[t], acc[i][t], 0, 0, 0);
        }
    }

    const float* hb = par + PB_HD0 + h * 7456;
#pragma unroll
    for (int t = 0; t < 4; ++t) {
        int oc = wave * 64 + t * 16 + n15;
        float b1 = hb[oc], g = hb[256 + oc], be = hb[512 + oc];
        float m = hb[768 + oc], v = hb[1024 + oc];
        float scale = g / sqrtf(v + 1e-5f);
        float s = 0.f;
#pragma unroll
        for (int i = 0; i < 4; ++i)
#pragma unroll
            for (int r = 0; r < 4; ++r) {
                int pos = i * 16 + q * 4 + r;
                if (pos < 49)
                    s += fmaxf((acc[i][t][r] + b1 - m) * scale + be, 0.f);
            }
        s += __shfl_xor(s, 16);
        s += __shfl_xor(s, 32);
        if (q == 0) means[oc] = s / 49.f;
    }
    __syncthreads();

    int oc_out = ocArr[h];
    const float* w2 = hb + 1280;
    for (int k = wave; k < oc_out; k += 4) {
        float s = 0.f;
        for (int c = lane; c < 256; c += 64) s += means[c] * w2[k * 256 + c];
#pragma unroll
        for (int off = 32; off > 0; off >>= 1) s += __shfl_down(s, off);
        if (lane == 0)
            head_out[(long)n * 32 + offArr[h] + k] = s + w2[oc_out * 256 + k];
    }
}

// =====================================================================
// Fallback path (small ws): separate ROI-align + head reading roi_in
// =====================================================================
__global__ __launch_bounds__(256)
void kRoi(const void* __restrict__ feat, const int* __restrict__ flag,
          const float* __restrict__ boxes, const int* __restrict__ clsArr,
          const float* __restrict__ par, float* __restrict__ roi_in) {
    const int n = blockIdx.x, tid = threadIdx.x;
    const int bf = *flag;
    __shared__ int   x0s[14], x1s[14], y0s[14], y1s[14], vxs[14], vys[14];
    __shared__ float lxs[14], lys[14], cxs[7], cys[7];

    const float bx1 = boxes[n * 5 + 1], by1 = boxes[n * 5 + 2];
    const float bx2 = boxes[n * 5 + 3], by2 = boxes[n * 5 + 4];
    const int b = (int)boxes[n * 5 + 0];

    ROI_META
    __syncthreads();

    for (int t = tid; t < CIN * 49; t += 256) {
        int c = t / 49, p = t % 49, oy = p / 7, ox = p % 7;
        long fb = ((long)b * CIN + c) * HW;
        float acc = 0.f;
#pragma unroll
        for (int dy = 0; dy < 2; ++dy) {
            int sy = oy * 2 + dy;
            float ly = lys[sy]; int yA = y0s[sy], yB = y1s[sy], vy = vys[sy];
#pragma unroll
            for (int dx = 0; dx < 2; ++dx) {
                int sx = ox * 2 + dx;
                float lx = lxs[sx]; int xA = x0s[sx], xB = x1s[sx];
                float v = (1.f - ly) * (1.f - lx) * gload(feat, fb + yA * FW + xA, bf)
                        + (1.f - ly) * lx         * gload(feat, fb + yA * FW + xB, bf)
                        + ly * (1.f - lx)         * gload(feat, fb + yB * FW + xA, bf)
                        + ly * lx                 * gload(feat, fb + yB * FW + xB, bf);
                if (!(vy && vxs[sx])) v = 0.f;
                acc += v;
            }
        }
        roi_in[((long)n * CROI + c) * 49 + p] = acc * 0.25f;
    }
    int cls = clsArr[n];
    for (int t = tid; t < 5 * 49; t += 256) {
        int ch = t / 49, p = t % 49, i = p / 7, j = p % 7;
        float v;
        if (ch == 0)      v = cxs[j];
        else if (ch == 1) v = cys[i];
        else              v = (cls == ch - 2) ? 1.f : 0.f;
        roi_in[((long)n * CROI + 64 + ch) * 49 + p] = v;
    }
}

__global__ __launch_bounds__(256, 4)
void kHeadM(const float* __restrict__ roi_in, const u16* __restrict__ whb,
            const float* __restrict__ par, float* __restrict__ head_out) {
    const int h = blockIdx.x, n = blockIdx.y, tid = threadIdx.x;
    const int wave = tid >> 6, lane = tid & 63;
    const int q = lane >> 4, n15 = lane & 15;
    const int ocArr[4] = {2, 2, 4, 24};
    const int offArr[4] = {0, 2, 4, 8};
    __shared__ __align__(16) u16 r_lds[9][9][104];
    __shared__ float means[256];

    for (int i = tid; i < 9 * 9 * 104 / 8; i += 256)
        ((uint4*)r_lds)[i] = (uint4){0, 0, 0, 0};
    __syncthreads();
    const float* rp = roi_in + (long)n * CROI * 49;
    for (int i = tid; i < CROI * 49; i += 256) {
        int c = i / 49, p = i % 49;
        r_lds[p / 7 + 1][p % 7 + 1][c] = f2b(rp[i]);
    }
    __syncthreads();

    int oyA[4], oxA[4];
#pragma unroll
    for (int i = 0; i < 4; ++i) {
        int pos = i * 16 + n15; if (pos > 48) pos = 48;
        oyA[i] = pos / 7; oxA[i] = pos % 7;
    }

    f32x4 acc[4][4];
#pragma unroll
    for (int i = 0; i < 4; ++i)
#pragma unroll
        for (int t = 0; t < 4; ++t) acc[i][t] = (f32x4){0.f, 0.f, 0.f, 0.f};

#pragma unroll 1
    for (int tap = 0; tap < 9; ++tap) {
        const int ky = tap / 3, kx = tap % 3;
        const u16* wt = whb + ((long)h * 9 + tap) * 24576;
#pragma unroll
        for (int cs = 0; cs < 3; ++cs) {
            short8 afr[4], bfr[4];
#pragma unroll
            for (int i = 0; i < 4; ++i)
                afr[i] = *(const short8*)&r_lds[oyA[i] + ky][oxA[i] + kx][cs * 32 + q * 8];
#pragma unroll
            for (int t = 0; t < 4; ++t)
                bfr[t] = *(const short8*)(wt + ((cs << 8) + wave * 64 + t * 16 + n15) * 32 + q * 8);
#pragma unroll
            for (int i = 0; i < 4; ++i)
#pragma unroll
                for (int t = 0; t < 4; ++t)
                    acc[i][t] = __builtin_amdgcn_mfma_f32_16x16x32_bf16(
                        afr[i], bfr[t], acc[i][t], 0, 0, 0);
        }
    }

    const float* hb = par + PB_HD0 + h * 7456;
#pragma unroll
    for (int t = 0; t < 4; ++t) {
        int oc = wave * 64 + t * 16 + n15;
        float b1 = hb[oc], g = hb[256 + oc], be = hb[512 + oc];
        float m = hb[768 + oc], v = hb[1024 + oc];
        float scale = g / sqrtf(v + 1e-5f);
        float s = 0.f;
#pragma unroll
        for (int i = 0; i < 4; ++i)
#pragma unroll
            for (int r = 0; r < 4; ++r) {
                int pos = i * 16 + q * 4 + r;
                if (pos < 49)
                    s += fmaxf((acc[i][t][r] + b1 - m) * scale + be, 0.f);
            }
        s += __shfl_xor(s, 16);
        s += __shfl_xor(s, 32);
        if (q == 0) means[oc] = s / 49.f;
    }
    __syncthreads();

    int oc_out = ocArr[h];
    const float* w2 = hb + 1280;
    for (int k = wave; k < oc_out; k += 4) {
        float s = 0.f;
        for (int c = lane; c < 256; c += 64) s += means[c] * w2[k * 256 + c];
#pragma unroll
        for (int off = 32; off > 0; off >>= 1) s += __shfl_down(s, off);
        if (lane == 0)
            head_out[(long)n * 32 + offArr[h] + k] = s + w2[oc_out * 256 + k];
    }
}

// =====================================================================
// Final scalar math + small outputs
// =====================================================================
__global__ void kFinal(const float* __restrict__ head_out, const float* __restrict__ boxes,
                       const int* __restrict__ clsArr, const float* __restrict__ par,
                       void* __restrict__ out, const int* __restrict__ flag) {
    int n = blockIdx.x * 256 + threadIdx.x;
    if (n >= NROI) return;
    const int bf = *flag;
    const float* ho = head_out + (long)n * 32;
    float dep0 = ho[0], dep1 = ho[1];
    int b = (int)boxes[n * 5 + 0];
    int cls = clsArr[n];

    for (int j = 0; j < 24; ++j) gstore(out, O_HEAD + n * 24 + j, ho[8 + j], bf);
    gstore(out, O_OFF3 + n * 2 + 0, ho[2], bf);
    gstore(out, O_OFF3 + n * 2 + 1, ho[3], bf);
    gstore(out, O_S3D + n * 3 + 0, ho[4], bf);
    gstore(out, O_S3D + n * 3 + 1, ho[5], bf);
    gstore(out, O_S3D + n * 3 + 2, ho[6], bf);
    gstore(out, O_H3D + n, ho[7], bf);

    float cry0 = par[PB_CRN + b * 4 + 1], cry1 = par[PB_CRN + b * 4 + 3];
    float sy = cry1 - cry0;
    float bi2 = boxes[n * 5 + 2] / (float)FH * sy + cry0;
    float bi4 = boxes[n * 5 + 4] / (float)FH * sy + cry0;
    float box_h = fmaxf(bi4 - bi2, 1.f);
    float f_u = par[PB_CAL + b * 12 + 0];
    float size3d0 = par[PB_MSZ + cls * 3 + 0] + ho[4];
    float depth_geo = size3d0 / box_h * f_u;
    float sig = 1.f / (1.f + expf(-dep0));
    float d0 = 1.f / (sig + 1e-6f) - 1.f + depth_geo;
    float dgls = ho[7] + 2.f * (logf(f_u) - logf(box_h));
    float mx = fmaxf(dep1, dgls);
    float lse = mx + logf(expf(dep1 - mx) + expf(dgls - mx));
    gstore(out, O_DEP + n * 2 + 0, d0, bf);
    gstore(out, O_DEP + n * 2 + 1, lse, bf);
}

// =====================================================================
extern "C" void kernel_launch(void* const* d_in, const int* in_sizes, int n_in,
                              void* d_out, int out_size, void* d_ws, size_t ws_size,
                              hipStream_t stream) {
    (void)in_sizes; (void)n_in; (void)out_size;
    float* ws = (float*)d_ws;
    float* par = ws + WS_PAR;
    int* flag = (int*)(ws + WS_FLAG);
    u16* wb16 = (u16*)(ws + WS_WB16);
    u16* whb  = (u16*)(ws + WS_W1H);
    u16* featT = (u16*)(ws + WS_FEATT);
    const void* feat = d_in[0];
    const bool bigws = ws_size >= (size_t)WS_END * 4;

    WPtrs WP;
    WP.bw[0] = d_in[4]; WP.bw[1] = d_in[8]; WP.bw[2] = d_in[12];
    WP.hw[0] = d_in[16]; WP.hw[1] = d_in[24]; WP.hw[2] = d_in[32]; WP.hw[3] = d_in[40];

    Segs SG; int si = 0;
    auto add = [&](const void* s, int n, int dst) {
        SG.s[si].src = s; SG.s[si].n = n; SG.s[si].dst = dst; ++si;
    };
    add(d_in[1], 96, PB_CAL); add(d_in[2], 32, PB_CRN); add(d_in[3], 9, PB_MSZ);
    const int ocb[3] = {3, 2, 2};
    for (int b = 0; b < 3; ++b) {
        int base = PB_BR0 + b * 1040;
        int i0 = 4 + 4 * b;
        add(d_in[i0 + 1], 256, base);
        add(d_in[i0 + 2], ocb[b] * 256, base + 256);
        add(d_in[i0 + 3], ocb[b], base + 256 + ocb[b] * 256);
    }
    const int och[4] = {2, 2, 4, 24};
    for (int h = 0; h < 4; ++h) {
        int base = PB_HD0 + h * 7456;
        int i0 = 16 + 8 * h;
        add(d_in[i0 + 1], 256, base);
        add(d_in[i0 + 2], 256, base + 256);
        add(d_in[i0 + 3], 256, base + 512);
        add(d_in[i0 + 4], 256, base + 768);
        add(d_in[i0 + 5], 256, base + 1024);
        add(d_in[i0 + 6], och[h] * 256, base + 1280);
        add(d_in[i0 + 7], och[h], base + 1280 + och[h] * 256);
    }
    SG.cnt = si;

    kPrepWP<<<5760 + 40, 256, 0, stream>>>(WP, SG, feat, flag,
                                           ws + WS_W1T, wb16, whb, par);

    // mega dispatch: conv (z<8) + f32 strip (z==8) + transpose (z==9 if bigws)
    kBranch3M<<<dim3(5, 48, bigws ? 10 : 9), 512, 0, stream>>>(
        feat, flag, wb16, par + PB_BR0, ws + WS_W1T, d_out, ws);

    kNmsTopA<<<dim3(24, NCHUNK), 256, 0, stream>>>(ws + WS_HEAT, ws + WS_NH);
    kTopBC<<<8, 192, 0, stream>>>(ws + WS_NH, ws + WS_OFF2, ws + WS_SIZ2,
                                  ws + WS_BOX, (int*)(ws + WS_CLS));
    if (bigws) {
        kHeadM2<<<dim3(4, NROI), 256, 0, stream>>>(featT, ws + WS_BOX,
                                                   (int*)(ws + WS_CLS), whb, par,
                                                   ws + WS_HOUT);
    } else {
        kRoi<<<400, 256, 0, stream>>>(feat, flag, ws + WS_BOX, (int*)(ws + WS_CLS),
                                      par, ws + WS_ROI);
        kHeadM<<<dim3(4, NROI), 256, 0, stream>>>(ws + WS_ROI, whb, par, ws + WS_HOUT);
    }
    kFinal<<<2, 256, 0, stream>>>(ws + WS_HOUT, ws + WS_BOX, (int*)(ws + WS_CLS),
                                  par, d_out, flag);
}